// Round 5
// baseline (148.383 us; speedup 1.0000x reference)
//
#include <hip/hip_runtime.h>
#include <hip/hip_bf16.h>
#include <stdint.h>

#define D_MODEL 1024
#define NH 16
#define DK 64
#define BB 2
#define SS 2048
#define MROWS (BB*SS)  // 4096

typedef __attribute__((ext_vector_type(8))) short bf16x8;
typedef __attribute__((ext_vector_type(4))) float f32x4;

__device__ __forceinline__ short to_bf16(float f) {
  __hip_bfloat16 h = __float2bfloat16(f);
  union { __hip_bfloat16 b; short s; } u; u.b = h; return u.s;
}

__device__ __forceinline__ f32x4 mfma16(bf16x8 a, bf16x8 b, f32x4 c) {
  return __builtin_amdgcn_mfma_f32_16x16x32_bf16(a, b, c, 0, 0, 0);
}

__device__ __forceinline__ void gload_lds16(const void* g, void* l) {
  __builtin_amdgcn_global_load_lds(
      (const __attribute__((address_space(1))) unsigned int*)g,
      (__attribute__((address_space(3))) unsigned int*)l,
      16, 0, 0);
}

// ---------------- batched f32 -> bf16 converts ----------------
__global__ __launch_bounds__(256) void cvt3(const float* __restrict__ a,
                                            const float* __restrict__ b,
                                            const float* __restrict__ c,
                                            short* __restrict__ oa,
                                            short* __restrict__ ob,
                                            short* __restrict__ oc) {
  const int z = blockIdx.z;
  const float* x = z == 0 ? a : z == 1 ? b : c;
  short* y = z == 0 ? oa : z == 1 ? ob : oc;
  const int i = (blockIdx.x * 256 + threadIdx.x) * 4;
  const float4 v = *(const float4*)(x + i);
  short4 o;
  o.x = to_bf16(v.x); o.y = to_bf16(v.y); o.z = to_bf16(v.z); o.w = to_bf16(v.w);
  *(short4*)(y + i) = o;
}

__global__ __launch_bounds__(256) void cvt4(const float* __restrict__ a,
                                            const float* __restrict__ b,
                                            const float* __restrict__ c,
                                            const float* __restrict__ d,
                                            short* __restrict__ oa,
                                            short* __restrict__ ob,
                                            short* __restrict__ oc,
                                            short* __restrict__ od) {
  const int z = blockIdx.z;
  const float* x = z == 0 ? a : z == 1 ? b : z == 2 ? c : d;
  short* y = z == 0 ? oa : z == 1 ? ob : z == 2 ? oc : od;
  const int i = (blockIdx.x * 256 + threadIdx.x) * 4;
  const float4 v = *(const float4*)(x + i);
  short4 o;
  o.x = to_bf16(v.x); o.y = to_bf16(v.y); o.z = to_bf16(v.z); o.w = to_bf16(v.w);
  *(short4*)(y + i) = o;
}

// ---------------- batched QKV projection: Y = X * W^T + b, BK=64 ----------
// z=0: Q -> (b,h,s,dk) scaled by 0.125*log2(e);  z=1: K -> (b,h,s,dk);
// z=2: V -> (b,h,dk,s)
__global__ __launch_bounds__(256) void gemm_qkv(const short* __restrict__ Xq,
                                                const short* __restrict__ Xk,
                                                const short* __restrict__ Xv,
                                                const short* __restrict__ Wq,
                                                const short* __restrict__ Wk,
                                                const short* __restrict__ Wv,
                                                const float* __restrict__ bq,
                                                const float* __restrict__ bk,
                                                const float* __restrict__ bv,
                                                short* __restrict__ Qh,
                                                short* __restrict__ Kh,
                                                short* __restrict__ VT) {
  constexpr int K = 1024;
  __shared__ short As[128 * 64];
  __shared__ short Bs[128 * 64];
  const int z = blockIdx.z;
  const short* A    = z == 0 ? Xq : z == 1 ? Xk : Xv;
  const short* Wt   = z == 0 ? Wq : z == 1 ? Wk : Wv;
  const float* bias = z == 0 ? bq : z == 1 ? bk : bv;

  const int tid = threadIdx.x;
  const int w = tid >> 6, lane = tid & 63;
  const int m0 = blockIdx.x * 128, n0 = blockIdx.y * 128;
  const int wm = w >> 1, wn = w & 1;
  const int fr = lane & 15, fg = lane >> 4;
  const int srow = tid >> 3, scol = (tid & 7) * 8;

  f32x4 acc[4][4] = {};

  for (int k0 = 0; k0 < K; k0 += 64) {
    __syncthreads();
#pragma unroll
    for (int i = 0; i < 4; ++i) {
      const int row = i * 32 + srow;
      gload_lds16(A  + (size_t)(m0 + row) * K + k0 + scol, As + row * 64 + scol);
      gload_lds16(Wt + (size_t)(n0 + row) * K + k0 + scol, Bs + row * 64 + scol);
    }
    asm volatile("s_waitcnt vmcnt(0)" ::: "memory");
    __syncthreads();

    bf16x8 af[4][2], bfr[4][2];
#pragma unroll
    for (int i = 0; i < 4; ++i)
#pragma unroll
      for (int hh = 0; hh < 2; ++hh) {
        af[i][hh]  = *(const bf16x8*)(As + (wm * 64 + i * 16 + fr) * 64 + hh * 32 + fg * 8);
        bfr[i][hh] = *(const bf16x8*)(Bs + (wn * 64 + i * 16 + fr) * 64 + hh * 32 + fg * 8);
      }
    __builtin_amdgcn_s_setprio(1);
#pragma unroll
    for (int mi = 0; mi < 4; ++mi)
#pragma unroll
      for (int ni = 0; ni < 4; ++ni) {
        acc[mi][ni] = mfma16(af[mi][0], bfr[ni][0], acc[mi][ni]);
        acc[mi][ni] = mfma16(af[mi][1], bfr[ni][1], acc[mi][ni]);
      }
    __builtin_amdgcn_s_setprio(0);
  }

  const float scale = (z == 0) ? 0.18033688011112042f : 1.0f;  // 0.125*log2(e)
#pragma unroll
  for (int mi = 0; mi < 4; ++mi)
#pragma unroll
    for (int ni = 0; ni < 4; ++ni) {
      const int col = n0 + wn * 64 + ni * 16 + fr;
      const float bval = bias[col];
      const int h = col >> 6, d = col & 63;
#pragma unroll
      for (int r = 0; r < 4; ++r) {
        const int row = m0 + wm * 64 + mi * 16 + fg * 4 + r;
        const float val = (acc[mi][ni][r] + bval) * scale;
        const int b = row >> 11, s = row & (SS - 1);
        if (z < 2) {
          short* dst = (z == 0) ? Qh : Kh;
          dst[((size_t)(b * NH + h) * SS + s) * DK + d] = to_bf16(val);
        } else {
          VT[((size_t)(b * NH + h) * DK + d) * SS + s] = to_bf16(val);
        }
      }
    }
}

// ---------------- O-projection: 128x64 tiles, BK=64, f32 out ----------------
__global__ __launch_bounds__(256) void gemm_out(const short* __restrict__ A,
                                                const short* __restrict__ Wt,
                                                const float* __restrict__ bias,
                                                float* __restrict__ Y) {
  constexpr int K = 1024;
  __shared__ short As[128 * 64];
  __shared__ short Bs[64 * 64];
  const int tid = threadIdx.x;
  const int w = tid >> 6, lane = tid & 63;
  const int m0 = blockIdx.x * 128, n0 = blockIdx.y * 64;
  const int wm = w >> 1, wn = w & 1;
  const int fr = lane & 15, fg = lane >> 4;
  const int srow = tid >> 3, scol = (tid & 7) * 8;

  f32x4 acc[4][2] = {};

  for (int k0 = 0; k0 < K; k0 += 64) {
    __syncthreads();
#pragma unroll
    for (int i = 0; i < 4; ++i) {
      const int row = i * 32 + srow;
      gload_lds16(A + (size_t)(m0 + row) * K + k0 + scol, As + row * 64 + scol);
    }
#pragma unroll
    for (int i = 0; i < 2; ++i) {
      const int row = i * 32 + srow;
      gload_lds16(Wt + (size_t)(n0 + row) * K + k0 + scol, Bs + row * 64 + scol);
    }
    asm volatile("s_waitcnt vmcnt(0)" ::: "memory");
    __syncthreads();

    bf16x8 af[4][2], bfr[2][2];
#pragma unroll
    for (int i = 0; i < 4; ++i)
#pragma unroll
      for (int hh = 0; hh < 2; ++hh)
        af[i][hh] = *(const bf16x8*)(As + (wm * 64 + i * 16 + fr) * 64 + hh * 32 + fg * 8);
#pragma unroll
    for (int i = 0; i < 2; ++i)
#pragma unroll
      for (int hh = 0; hh < 2; ++hh)
        bfr[i][hh] = *(const bf16x8*)(Bs + (wn * 32 + i * 16 + fr) * 64 + hh * 32 + fg * 8);
    __builtin_amdgcn_s_setprio(1);
#pragma unroll
    for (int mi = 0; mi < 4; ++mi)
#pragma unroll
      for (int ni = 0; ni < 2; ++ni) {
        acc[mi][ni] = mfma16(af[mi][0], bfr[ni][0], acc[mi][ni]);
        acc[mi][ni] = mfma16(af[mi][1], bfr[ni][1], acc[mi][ni]);
      }
    __builtin_amdgcn_s_setprio(0);
  }

#pragma unroll
  for (int mi = 0; mi < 4; ++mi)
#pragma unroll
    for (int ni = 0; ni < 2; ++ni) {
      const int col = n0 + wn * 32 + ni * 16 + fr;
      const float bval = bias[col];
#pragma unroll
      for (int r = 0; r < 4; ++r) {
        const int row = m0 + wm * 64 + mi * 16 + fg * 4 + r;
        Y[(size_t)row * D_MODEL + col] = acc[mi][ni][r] + bval;
      }
    }
}

// ---------------- causal flash attention, split-K across wave pairs --------
// 32 q-rows/strip, KVBLK=64. Each strip handled by TWO waves (low/high half
// of its K-tile range); partial (m, l-row, O) merged once via LDS. Block =
// 2 strips {p, 63-p} x 2 waves; 1024 blocks (4/CU). Swapped QK^T, exp2
// softmax (Q pre-scaled 0.125*log2e), K prefetch, V early-issue, MFMA l-sum,
// defer-max (THR=11 log2 units).
__global__ __launch_bounds__(256, 2) void attn_kernel(const short* __restrict__ Qh,
                                                      const short* __restrict__ Kh,
                                                      const short* __restrict__ VT,
                                                      short* __restrict__ AO) {
  __shared__ short P_lds[4][2][16 * 64];   // 16 KB, per-wave P buffers
  __shared__ float M_lds[2][2][16];        // [strip][qt][fr]
  __shared__ f32x4 O_lds[2][5][2][64];     // [strip][t][qt][lane], 20 KB

  const int tid = threadIdx.x, w = tid >> 6, lane = tid & 63;
  const int fr = lane & 15, fg = lane >> 4;
  const int kr = fg * 4;

  // XCD swizzle: 1024 blocks, 128 consecutive logical ids per XCD
  const int bid = blockIdx.x;
  const int lid = ((bid & 7) << 7) | (bid >> 3);
  const int bh = lid >> 5;      // 0..31
  const int pidx = lid & 31;    // 0..31
  const int b = bh >> 4, h = bh & 15;

  const int ss = w >> 1;        // which strip of the block's pair
  const int half = w & 1;       // which half of the K range
  const int strip = (ss == 0) ? pidx : (63 - pidx);
  const int q0w = strip * 32;

  const short* Qp = Qh + (size_t)bh * SS * DK;
  const short* Kp = Kh + (size_t)bh * SS * DK;
  const short* Vp = VT + (size_t)bh * DK * SS;

  bf16x8 qf[2][2];
#pragma unroll
  for (int qt = 0; qt < 2; ++qt)
#pragma unroll
    for (int hh = 0; hh < 2; ++hh)
      qf[qt][hh] = *(const bf16x8*)(Qp + (size_t)(q0w + qt * 16 + fr) * DK + hh * 32 + fg * 8);

  // ones A-fragment (row 0 of the l-sum tile = 1.0, rest 0)
  const short onev = (fr == 0) ? (short)0x3F80 : (short)0;
  const bf16x8 af4 = {onev, onev, onev, onev, onev, onev, onev, onev};

  f32x4 o[5][2] = {};  // [d-tile 0..3, 4 = l-sum][qt]
  float m_run[2] = {-1e30f, -1e30f};

  const int T = (q0w >> 6) + 1;            // total K tiles for this strip
  const int tbeg = half ? (T >> 1) : 0;
  const int tend = half ? T : (T >> 1);
  const int Tm1 = T - 1;
  const int swz = (fr & 7) << 4;

  bf16x8 kf[4][2];
  if (tbeg < tend) {
#pragma unroll
    for (int kt = 0; kt < 4; ++kt)
#pragma unroll
      for (int hh = 0; hh < 2; ++hh)
        kf[kt][hh] = *(const bf16x8*)(Kp + (size_t)(tbeg * 64 + kt * 16 + fr) * DK + hh * 32 + fg * 8);
  }

  for (int ti = tbeg; ti < tend; ++ti) {
    const int k0 = ti * 64;
    const bool hasNext = (ti + 1) < tend;

    // prefetch next K tile (latency hides under QK + softmax)
    bf16x8 kn[4][2];
    if (hasNext) {
#pragma unroll
      for (int kt = 0; kt < 4; ++kt)
#pragma unroll
        for (int hh = 0; hh < 2; ++hh)
          kn[kt][hh] = *(const bf16x8*)(Kp + (size_t)(k0 + 64 + kt * 16 + fr) * DK + hh * 32 + fg * 8);
    }

    f32x4 st[4][2] = {};
    __builtin_amdgcn_s_setprio(1);
#pragma unroll
    for (int kt = 0; kt < 4; ++kt)
#pragma unroll
      for (int qt = 0; qt < 2; ++qt) {
        st[kt][qt] = mfma16(kf[kt][0], qf[qt][0], st[kt][qt]);
        st[kt][qt] = mfma16(kf[kt][1], qf[qt][1], st[kt][qt]);
      }
    __builtin_amdgcn_s_setprio(0);

    // V loads issued before the LDS fence: latency hides under softmax
    bf16x8 vf[2][4];
#pragma unroll
    for (int c = 0; c < 2; ++c)
#pragma unroll
      for (int t = 0; t < 4; ++t)
        vf[c][t] = *(const bf16x8*)(Vp + (size_t)(t * 16 + fr) * SS + k0 + c * 32 + fg * 8);

    if (ti == Tm1) {
#pragma unroll
      for (int kt = 0; kt < 4; ++kt)
#pragma unroll
        for (int qt = 0; qt < 2; ++qt)
#pragma unroll
          for (int r = 0; r < 4; ++r)
            if (k0 + kt * 16 + kr + r > q0w + qt * 16 + fr) st[kt][qt][r] = -1e30f;
    }

    float pmax[2];
#pragma unroll
    for (int qt = 0; qt < 2; ++qt) {
      float mt = st[0][qt][0];
#pragma unroll
      for (int kt = 0; kt < 4; ++kt)
#pragma unroll
        for (int r = 0; r < 4; ++r) mt = fmaxf(mt, st[kt][qt][r]);
      mt = fmaxf(mt, __shfl_xor(mt, 16));
      mt = fmaxf(mt, __shfl_xor(mt, 32));
      pmax[qt] = mt;
    }

    const bool ok = (pmax[0] <= m_run[0] + 11.0f) && (pmax[1] <= m_run[1] + 11.0f);
    if (!__all(ok)) {
#pragma unroll
      for (int qt = 0; qt < 2; ++qt) {
        const float mn = fmaxf(m_run[qt], pmax[qt]);
        const float al = __builtin_amdgcn_exp2f(m_run[qt] - mn);
        m_run[qt] = mn;
#pragma unroll
        for (int t = 0; t < 5; ++t)
#pragma unroll
          for (int r = 0; r < 4; ++r) o[t][qt][r] *= al;
      }
    }

#pragma unroll
    for (int qt = 0; qt < 2; ++qt) {
      char* base = (char*)P_lds[w][qt];
#pragma unroll
      for (int kt = 0; kt < 4; ++kt) {
        short4 sv;
        sv.x = to_bf16(__builtin_amdgcn_exp2f(st[kt][qt][0] - m_run[qt]));
        sv.y = to_bf16(__builtin_amdgcn_exp2f(st[kt][qt][1] - m_run[qt]));
        sv.z = to_bf16(__builtin_amdgcn_exp2f(st[kt][qt][2] - m_run[qt]));
        sv.w = to_bf16(__builtin_amdgcn_exp2f(st[kt][qt][3] - m_run[qt]));
        *(short4*)(base + ((fr * 128 + kt * 32 + fg * 8) ^ swz)) = sv;
      }
    }
    asm volatile("s_waitcnt lgkmcnt(0)" ::: "memory");

    bf16x8 pf[2][2];
#pragma unroll
    for (int qt = 0; qt < 2; ++qt)
#pragma unroll
      for (int c = 0; c < 2; ++c)
        pf[qt][c] = *(const bf16x8*)((const char*)P_lds[w][qt] + ((fr * 128 + c * 64 + fg * 16) ^ swz));

    __builtin_amdgcn_s_setprio(1);
#pragma unroll
    for (int c = 0; c < 2; ++c)
#pragma unroll
      for (int qt = 0; qt < 2; ++qt) {
#pragma unroll
        for (int t = 0; t < 4; ++t)
          o[t][qt] = mfma16(vf[c][t], pf[qt][c], o[t][qt]);
        o[4][qt] = mfma16(af4, pf[qt][c], o[4][qt]);
      }
    __builtin_amdgcn_s_setprio(0);

    if (hasNext) {
#pragma unroll
      for (int kt = 0; kt < 4; ++kt)
#pragma unroll
        for (int hh = 0; hh < 2; ++hh) kf[kt][hh] = kn[kt][hh];
    }
  }

  // ---- merge the two K-halves of each strip ----
  if (half == 1) {
    if (fg == 0) {
      M_lds[ss][0][fr] = m_run[0];
      M_lds[ss][1][fr] = m_run[1];
    }
#pragma unroll
    for (int t = 0; t < 5; ++t)
#pragma unroll
      for (int qt = 0; qt < 2; ++qt)
        O_lds[ss][t][qt][lane] = o[t][qt];
  }
  __syncthreads();
  if (half == 0) {
#pragma unroll
    for (int qt = 0; qt < 2; ++qt) {
      const float mB = M_lds[ss][qt][fr];
      const float mm = fmaxf(m_run[qt], mB);
      const float aA = __builtin_amdgcn_exp2f(m_run[qt] - mm);
      const float aB = __builtin_amdgcn_exp2f(mB - mm);
#pragma unroll
      for (int t = 0; t < 5; ++t)
        o[t][qt] = o[t][qt] * aA + O_lds[ss][t][qt][lane] * aB;
    }

    // l lives in o[4][qt][0] on lanes 0..15 (row 0); broadcast by shfl
#pragma unroll
    for (int qt = 0; qt < 2; ++qt) {
      const float l = __shfl(o[4][qt][0], fr);
      const float inv = 1.0f / l;
      const int s = q0w + qt * 16 + fr;
#pragma unroll
      for (int t = 0; t < 4; ++t) {
        short4 ov = {to_bf16(o[t][qt][0] * inv), to_bf16(o[t][qt][1] * inv),
                     to_bf16(o[t][qt][2] * inv), to_bf16(o[t][qt][3] * inv)};
        *(short4*)(AO + (size_t)(b * SS + s) * D_MODEL + h * 64 + t * 16 + kr) = ov;
      }
    }
  }
}

extern "C" void kernel_launch(void* const* d_in, const int* in_sizes, int n_in,
                              void* d_out, int out_size, void* d_ws, size_t ws_size,
                              hipStream_t stream) {
  const float* q  = (const float*)d_in[0];
  const float* k  = (const float*)d_in[1];
  const float* v  = (const float*)d_in[2];
  const float* Wq = (const float*)d_in[4];
  const float* bq = (const float*)d_in[5];
  const float* Wk = (const float*)d_in[6];
  const float* bk = (const float*)d_in[7];
  const float* Wv = (const float*)d_in[8];
  const float* bv = (const float*)d_in[9];
  const float* Wo = (const float*)d_in[10];
  const float* bo = (const float*)d_in[11];

  char* ws = (char*)d_ws;
  const size_t MB = 1u << 20;
  short* Xq = (short*)(ws + 0 * MB);
  short* Xk = (short*)(ws + 8 * MB);
  short* Xv = (short*)(ws + 16 * MB);
  short* Bq = (short*)(ws + 24 * MB);
  short* Bk = (short*)(ws + 26 * MB);
  short* Bv = (short*)(ws + 28 * MB);
  short* Bo = (short*)(ws + 30 * MB);
  short* Qh = (short*)(ws + 32 * MB);
  short* Kh = (short*)(ws + 40 * MB);
  short* VT = (short*)(ws + 48 * MB);
  short* AO = (short*)(ws + 56 * MB);

  cvt3<<<dim3(MROWS * D_MODEL / 1024, 1, 3), 256, 0, stream>>>(q, k, v, Xq, Xk, Xv);
  cvt4<<<dim3(D_MODEL * D_MODEL / 1024, 1, 4), 256, 0, stream>>>(Wq, Wk, Wv, Wo, Bq, Bk, Bv, Bo);

  gemm_qkv<<<dim3(MROWS / 128, D_MODEL / 128, 3), 256, 0, stream>>>(
      Xq, Xk, Xv, Bq, Bk, Bv, bq, bk, bv, Qh, Kh, VT);

  attn_kernel<<<dim3(1024), 256, 0, stream>>>(Qh, Kh, VT, AO);

  gemm_out<<<dim3(MROWS / 128, D_MODEL / 64), 256, 0, stream>>>(AO, Bo, bo, (float*)d_out);
}

// Round 6
// 133.888 us; speedup vs baseline: 1.1083x; 1.1083x over previous
//
#include <hip/hip_runtime.h>
#include <hip/hip_bf16.h>
#include <stdint.h>

#define D_MODEL 1024
#define NH 16
#define DK 64
#define BB 2
#define SS 2048
#define MROWS (BB*SS)  // 4096

typedef __attribute__((ext_vector_type(8))) short bf16x8;
typedef __attribute__((ext_vector_type(4))) float f32x4;

__device__ __forceinline__ short to_bf16(float f) {
  __hip_bfloat16 h = __float2bfloat16(f);
  union { __hip_bfloat16 b; short s; } u; u.b = h; return u.s;
}

__device__ __forceinline__ f32x4 mfma16(bf16x8 a, bf16x8 b, f32x4 c) {
  return __builtin_amdgcn_mfma_f32_16x16x32_bf16(a, b, c, 0, 0, 0);
}

__device__ __forceinline__ void gload_lds16(const void* g, void* l) {
  __builtin_amdgcn_global_load_lds(
      (const __attribute__((address_space(1))) unsigned int*)g,
      (__attribute__((address_space(3))) unsigned int*)l,
      16, 0, 0);
}

// ---------------- batched f32 -> bf16 converts ----------------
__global__ __launch_bounds__(256) void cvt3(const float* __restrict__ a,
                                            const float* __restrict__ b,
                                            const float* __restrict__ c,
                                            short* __restrict__ oa,
                                            short* __restrict__ ob,
                                            short* __restrict__ oc) {
  const int z = blockIdx.z;
  const float* x = z == 0 ? a : z == 1 ? b : c;
  short* y = z == 0 ? oa : z == 1 ? ob : oc;
  const int i = (blockIdx.x * 256 + threadIdx.x) * 4;
  const float4 v = *(const float4*)(x + i);
  short4 o;
  o.x = to_bf16(v.x); o.y = to_bf16(v.y); o.z = to_bf16(v.z); o.w = to_bf16(v.w);
  *(short4*)(y + i) = o;
}

__global__ __launch_bounds__(256) void cvt4(const float* __restrict__ a,
                                            const float* __restrict__ b,
                                            const float* __restrict__ c,
                                            const float* __restrict__ d,
                                            short* __restrict__ oa,
                                            short* __restrict__ ob,
                                            short* __restrict__ oc,
                                            short* __restrict__ od) {
  const int z = blockIdx.z;
  const float* x = z == 0 ? a : z == 1 ? b : z == 2 ? c : d;
  short* y = z == 0 ? oa : z == 1 ? ob : z == 2 ? oc : od;
  const int i = (blockIdx.x * 256 + threadIdx.x) * 4;
  const float4 v = *(const float4*)(x + i);
  short4 o;
  o.x = to_bf16(v.x); o.y = to_bf16(v.y); o.z = to_bf16(v.z); o.w = to_bf16(v.w);
  *(short4*)(y + i) = o;
}

// ---------------- batched QKV projection: Y = X * W^T + b, BK=64 ----------
// z=0: Q -> (b,h,s,dk) scaled by 0.125*log2(e);  z=1: K -> (b,h,s,dk);
// z=2: V -> (b,h,dk,s)
__global__ __launch_bounds__(256) void gemm_qkv(const short* __restrict__ Xq,
                                                const short* __restrict__ Xk,
                                                const short* __restrict__ Xv,
                                                const short* __restrict__ Wq,
                                                const short* __restrict__ Wk,
                                                const short* __restrict__ Wv,
                                                const float* __restrict__ bq,
                                                const float* __restrict__ bk,
                                                const float* __restrict__ bv,
                                                short* __restrict__ Qh,
                                                short* __restrict__ Kh,
                                                short* __restrict__ VT) {
  constexpr int K = 1024;
  __shared__ short As[128 * 64];
  __shared__ short Bs[128 * 64];
  const int z = blockIdx.z;
  const short* A    = z == 0 ? Xq : z == 1 ? Xk : Xv;
  const short* Wt   = z == 0 ? Wq : z == 1 ? Wk : Wv;
  const float* bias = z == 0 ? bq : z == 1 ? bk : bv;

  const int tid = threadIdx.x;
  const int w = tid >> 6, lane = tid & 63;
  const int m0 = blockIdx.x * 128, n0 = blockIdx.y * 128;
  const int wm = w >> 1, wn = w & 1;
  const int fr = lane & 15, fg = lane >> 4;
  const int srow = tid >> 3, scol = (tid & 7) * 8;

  f32x4 acc[4][4] = {};

  for (int k0 = 0; k0 < K; k0 += 64) {
    __syncthreads();
#pragma unroll
    for (int i = 0; i < 4; ++i) {
      const int row = i * 32 + srow;
      gload_lds16(A  + (size_t)(m0 + row) * K + k0 + scol, As + row * 64 + scol);
      gload_lds16(Wt + (size_t)(n0 + row) * K + k0 + scol, Bs + row * 64 + scol);
    }
    asm volatile("s_waitcnt vmcnt(0)" ::: "memory");
    __syncthreads();

    bf16x8 af[4][2], bfr[4][2];
#pragma unroll
    for (int i = 0; i < 4; ++i)
#pragma unroll
      for (int hh = 0; hh < 2; ++hh) {
        af[i][hh]  = *(const bf16x8*)(As + (wm * 64 + i * 16 + fr) * 64 + hh * 32 + fg * 8);
        bfr[i][hh] = *(const bf16x8*)(Bs + (wn * 64 + i * 16 + fr) * 64 + hh * 32 + fg * 8);
      }
    __builtin_amdgcn_s_setprio(1);
#pragma unroll
    for (int mi = 0; mi < 4; ++mi)
#pragma unroll
      for (int ni = 0; ni < 4; ++ni) {
        acc[mi][ni] = mfma16(af[mi][0], bfr[ni][0], acc[mi][ni]);
        acc[mi][ni] = mfma16(af[mi][1], bfr[ni][1], acc[mi][ni]);
      }
    __builtin_amdgcn_s_setprio(0);
  }

  const float scale = (z == 0) ? 0.18033688011112042f : 1.0f;  // 0.125*log2(e)
#pragma unroll
  for (int mi = 0; mi < 4; ++mi)
#pragma unroll
    for (int ni = 0; ni < 4; ++ni) {
      const int col = n0 + wn * 64 + ni * 16 + fr;
      const float bval = bias[col];
      const int h = col >> 6, d = col & 63;
#pragma unroll
      for (int r = 0; r < 4; ++r) {
        const int row = m0 + wm * 64 + mi * 16 + fg * 4 + r;
        const float val = (acc[mi][ni][r] + bval) * scale;
        const int b = row >> 11, s = row & (SS - 1);
        if (z < 2) {
          short* dst = (z == 0) ? Qh : Kh;
          dst[((size_t)(b * NH + h) * SS + s) * DK + d] = to_bf16(val);
        } else {
          VT[((size_t)(b * NH + h) * DK + d) * SS + s] = to_bf16(val);
        }
      }
    }
}

// ---------------- O-projection: 128x64 tiles, BK=64, f32 out ----------------
__global__ __launch_bounds__(256) void gemm_out(const short* __restrict__ A,
                                                const short* __restrict__ Wt,
                                                const float* __restrict__ bias,
                                                float* __restrict__ Y) {
  constexpr int K = 1024;
  __shared__ short As[128 * 64];
  __shared__ short Bs[64 * 64];
  const int tid = threadIdx.x;
  const int w = tid >> 6, lane = tid & 63;
  const int m0 = blockIdx.x * 128, n0 = blockIdx.y * 64;
  const int wm = w >> 1, wn = w & 1;
  const int fr = lane & 15, fg = lane >> 4;
  const int srow = tid >> 3, scol = (tid & 7) * 8;

  f32x4 acc[4][2] = {};

  for (int k0 = 0; k0 < K; k0 += 64) {
    __syncthreads();
#pragma unroll
    for (int i = 0; i < 4; ++i) {
      const int row = i * 32 + srow;
      gload_lds16(A + (size_t)(m0 + row) * K + k0 + scol, As + row * 64 + scol);
    }
#pragma unroll
    for (int i = 0; i < 2; ++i) {
      const int row = i * 32 + srow;
      gload_lds16(Wt + (size_t)(n0 + row) * K + k0 + scol, Bs + row * 64 + scol);
    }
    asm volatile("s_waitcnt vmcnt(0)" ::: "memory");
    __syncthreads();

    bf16x8 af[4][2], bfr[2][2];
#pragma unroll
    for (int i = 0; i < 4; ++i)
#pragma unroll
      for (int hh = 0; hh < 2; ++hh)
        af[i][hh] = *(const bf16x8*)(As + (wm * 64 + i * 16 + fr) * 64 + hh * 32 + fg * 8);
#pragma unroll
    for (int i = 0; i < 2; ++i)
#pragma unroll
      for (int hh = 0; hh < 2; ++hh)
        bfr[i][hh] = *(const bf16x8*)(Bs + (wn * 32 + i * 16 + fr) * 64 + hh * 32 + fg * 8);
    __builtin_amdgcn_s_setprio(1);
#pragma unroll
    for (int mi = 0; mi < 4; ++mi)
#pragma unroll
      for (int ni = 0; ni < 2; ++ni) {
        acc[mi][ni] = mfma16(af[mi][0], bfr[ni][0], acc[mi][ni]);
        acc[mi][ni] = mfma16(af[mi][1], bfr[ni][1], acc[mi][ni]);
      }
    __builtin_amdgcn_s_setprio(0);
  }

#pragma unroll
  for (int mi = 0; mi < 4; ++mi)
#pragma unroll
    for (int ni = 0; ni < 2; ++ni) {
      const int col = n0 + wn * 32 + ni * 16 + fr;
      const float bval = bias[col];
#pragma unroll
      for (int r = 0; r < 4; ++r) {
        const int row = m0 + wm * 64 + mi * 16 + fg * 4 + r;
        Y[(size_t)row * D_MODEL + col] = acc[mi][ni][r] + bval;
      }
    }
}

// ---------------- causal flash attention, block-cooperative LDS staging ----
// Block = 64 q rows (one pair-strip) of one head; 4 waves x 16 q rows, all
// sharing the same causal K-range. K/V tiles (64 keys) staged once per block
// into LDS via global_load_lds (DMA, double-buffered, one vmcnt(0)+barrier
// per tile) with XOR-swizzled layout (pre-swizzled global source). Swapped
// QK^T, exp2 softmax (Q pre-scaled 0.125*log2e), wave-private P_lds, MFMA
// l-sum, defer-max. 1024 blocks (4/CU, 40KB LDS).
__global__ __launch_bounds__(256, 4) void attn_kernel(const short* __restrict__ Qh,
                                                      const short* __restrict__ Kh,
                                                      const short* __restrict__ VT,
                                                      short* __restrict__ AO) {
  __shared__ short Ks[2][64 * 64];   // [buf][key-row][d], swizzled, 16 KB
  __shared__ short Vs[2][64 * 64];   // [buf][d-row][key], swizzled, 16 KB
  __shared__ short P_lds[4][16 * 64];  // wave-private P^T, 8 KB

  const int tid = threadIdx.x, w = tid >> 6, lane = tid & 63;
  const int fr = lane & 15, fg = lane >> 4;
  const int kr = fg * 4;
  const int swz = (fr & 7) << 4;

  // XCD swizzle: bid%8 = XCD -> 4 heads per XCD; P interleaved [0,31,1,30,..]
  // so any 4 consecutive blocks have ~constant total tile count.
  const int bid = blockIdx.x;
  const int lid = ((bid & 7) << 7) | (bid >> 3);
  const int bh = lid >> 5;      // 0..31
  const int idx = lid & 31;     // 0..31
  const int P = (idx & 1) ? (31 - (idx >> 1)) : (idx >> 1);
  const int b = bh >> 4, h = bh & 15;
  const int qw = P * 64 + w * 16;  // wave's q base

  const short* Qp = Qh + (size_t)bh * SS * DK;
  const short* Kp = Kh + (size_t)bh * SS * DK;
  const short* Vp = VT + (size_t)bh * DK * SS;

  // staging decomposition: 256 threads x 16B x 2 passes = 8KB per tile
  const int sc_c = tid & 7;    // 16B chunk within 128B row
  const int sc_r = tid >> 3;   // row 0..31 (pass adds 32)

  bf16x8 qf[2];
#pragma unroll
  for (int hh = 0; hh < 2; ++hh)
    qf[hh] = *(const bf16x8*)(Qp + (size_t)(qw + fr) * DK + hh * 32 + fg * 8);

  // ones A-fragment (row 0 of the l-sum tile = 1.0, rest 0)
  const short onev = (fr == 0) ? (short)0x3F80 : (short)0;
  const bf16x8 af4 = {onev, onev, onev, onev, onev, onev, onev, onev};

  f32x4 o[5] = {};  // d-tiles 0..3 + l-sum; lane holds O^T[d=t*16+kr+r][q=fr]
  float m_run = -1e30f;

  const int T = P + 1;

#define STAGE_KV(buf, t0)                                                     \
  do {                                                                        \
    const int kk0 = (t0) * 64;                                                \
    _Pragma("unroll") for (int p = 0; p < 2; ++p) {                           \
      const int row = p * 32 + sc_r;                                          \
      const int sc = sc_c ^ (row & 7);                                        \
      gload_lds16(Kp + (size_t)(kk0 + row) * DK + sc * 8,                     \
                  &Ks[buf][row * 64 + sc_c * 8]);                             \
      gload_lds16(Vp + (size_t)row * SS + kk0 + sc * 8,                       \
                  &Vs[buf][row * 64 + sc_c * 8]);                             \
    }                                                                         \
  } while (0)

  STAGE_KV(0, 0);
  asm volatile("s_waitcnt vmcnt(0)" ::: "memory");
  __syncthreads();

  for (int ti = 0; ti < T; ++ti) {
    const int cur = ti & 1;
    if (ti + 1 < T) STAGE_KV(cur ^ 1, ti + 1);  // DMA overlaps compute

    const char* KsB = (const char*)Ks[cur];
    const char* VsB = (const char*)Vs[cur];

    // QK^T: st[kt][r] = S^T[kk = kt*16+kr+r][q = fr]
    f32x4 st[4];
    __builtin_amdgcn_s_setprio(1);
#pragma unroll
    for (int kt = 0; kt < 4; ++kt) {
      const bf16x8 k0f = *(const bf16x8*)(KsB + (kt * 16 + fr) * 128 + ((fg * 16) ^ swz));
      const bf16x8 k1f = *(const bf16x8*)(KsB + (kt * 16 + fr) * 128 + ((64 + fg * 16) ^ swz));
      f32x4 z = {};
      z = mfma16(k0f, qf[0], z);
      z = mfma16(k1f, qf[1], z);
      st[kt] = z;
    }
    __builtin_amdgcn_s_setprio(0);

    if (ti == T - 1) {  // diagonal tile: mask kk > q (within-block offsets)
#pragma unroll
      for (int kt = 0; kt < 4; ++kt)
#pragma unroll
        for (int r = 0; r < 4; ++r)
          if (kt * 16 + kr + r > w * 16 + fr) st[kt][r] = -1e30f;
    }

    float pmax = st[0][0];
#pragma unroll
    for (int kt = 0; kt < 4; ++kt)
#pragma unroll
      for (int r = 0; r < 4; ++r) pmax = fmaxf(pmax, st[kt][r]);
    pmax = fmaxf(pmax, __shfl_xor(pmax, 16));
    pmax = fmaxf(pmax, __shfl_xor(pmax, 32));

    if (!__all(pmax <= m_run + 11.0f)) {
      const float mn = fmaxf(m_run, pmax);
      const float al = __builtin_amdgcn_exp2f(m_run - mn);
      m_run = mn;
#pragma unroll
      for (int t = 0; t < 5; ++t)
#pragma unroll
        for (int r = 0; r < 4; ++r) o[t][r] *= al;
    }

    // P^T -> wave-private LDS (row q=fr, swizzled), packed 8B writes
    {
      char* base = (char*)P_lds[w];
#pragma unroll
      for (int kt = 0; kt < 4; ++kt) {
        short4 sv;
        sv.x = to_bf16(__builtin_amdgcn_exp2f(st[kt][0] - m_run));
        sv.y = to_bf16(__builtin_amdgcn_exp2f(st[kt][1] - m_run));
        sv.z = to_bf16(__builtin_amdgcn_exp2f(st[kt][2] - m_run));
        sv.w = to_bf16(__builtin_amdgcn_exp2f(st[kt][3] - m_run));
        *(short4*)(base + ((fr * 128 + kt * 32 + fg * 8) ^ swz)) = sv;
      }
    }
    asm volatile("s_waitcnt lgkmcnt(0)" ::: "memory");

    // PV: O^T[d][q] += V^T[d][kk] * P^T[kk][q], V from swizzled LDS
    __builtin_amdgcn_s_setprio(1);
#pragma unroll
    for (int c = 0; c < 2; ++c) {
      const bf16x8 pf = *(const bf16x8*)((const char*)P_lds[w] +
                                         ((fr * 128 + c * 64 + fg * 16) ^ swz));
#pragma unroll
      for (int t = 0; t < 4; ++t) {
        const bf16x8 vfb = *(const bf16x8*)(VsB + (t * 16 + fr) * 128 +
                                            ((c * 64 + fg * 16) ^ swz));
        o[t] = mfma16(vfb, pf, o[t]);
      }
      o[4] = mfma16(af4, pf, o[4]);
    }
    __builtin_amdgcn_s_setprio(0);

    asm volatile("s_waitcnt vmcnt(0)" ::: "memory");
    __syncthreads();
  }
#undef STAGE_KV

  // epilogue: l on row 0 (lanes 0..15) of o[4]; broadcast by shfl
  const float l = __shfl(o[4][0], fr);
  const float inv = 1.0f / l;
  const int s = qw + fr;
#pragma unroll
  for (int t = 0; t < 4; ++t) {
    short4 ov = {to_bf16(o[t][0] * inv), to_bf16(o[t][1] * inv),
                 to_bf16(o[t][2] * inv), to_bf16(o[t][3] * inv)};
    *(short4*)(AO + (size_t)(b * SS + s) * D_MODEL + h * 64 + t * 16 + kr) = ov;
  }
}

extern "C" void kernel_launch(void* const* d_in, const int* in_sizes, int n_in,
                              void* d_out, int out_size, void* d_ws, size_t ws_size,
                              hipStream_t stream) {
  const float* q  = (const float*)d_in[0];
  const float* k  = (const float*)d_in[1];
  const float* v  = (const float*)d_in[2];
  const float* Wq = (const float*)d_in[4];
  const float* bq = (const float*)d_in[5];
  const float* Wk = (const float*)d_in[6];
  const float* bk = (const float*)d_in[7];
  const float* Wv = (const float*)d_in[8];
  const float* bv = (const float*)d_in[9];
  const float* Wo = (const float*)d_in[10];
  const float* bo = (const float*)d_in[11];

  char* ws = (char*)d_ws;
  const size_t MB = 1u << 20;
  short* Xq = (short*)(ws + 0 * MB);
  short* Xk = (short*)(ws + 8 * MB);
  short* Xv = (short*)(ws + 16 * MB);
  short* Bq = (short*)(ws + 24 * MB);
  short* Bk = (short*)(ws + 26 * MB);
  short* Bv = (short*)(ws + 28 * MB);
  short* Bo = (short*)(ws + 30 * MB);
  short* Qh = (short*)(ws + 32 * MB);
  short* Kh = (short*)(ws + 40 * MB);
  short* VT = (short*)(ws + 48 * MB);
  short* AO = (short*)(ws + 56 * MB);

  cvt3<<<dim3(MROWS * D_MODEL / 1024, 1, 3), 256, 0, stream>>>(q, k, v, Xq, Xk, Xv);
  cvt4<<<dim3(D_MODEL * D_MODEL / 1024, 1, 4), 256, 0, stream>>>(Wq, Wk, Wv, Wo, Bq, Bk, Bv, Bo);

  gemm_qkv<<<dim3(MROWS / 128, D_MODEL / 128, 3), 256, 0, stream>>>(
      Xq, Xk, Xv, Bq, Bk, Bv, bq, bk, bv, Qh, Kh, VT);

  attn_kernel<<<dim3(1024), 256, 0, stream>>>(Qh, Kh, VT, AO);

  gemm_out<<<dim3(MROWS / 128, D_MODEL / 64), 256, 0, stream>>>(AO, Bo, bo, (float*)d_out);
}

// Round 7
// 126.156 us; speedup vs baseline: 1.1762x; 1.0613x over previous
//
#include <hip/hip_runtime.h>
#include <hip/hip_bf16.h>
#include <stdint.h>

#define D_MODEL 1024
#define NH 16
#define DK 64
#define BB 2
#define SS 2048
#define MROWS (BB*SS)  // 4096

typedef __attribute__((ext_vector_type(8))) short bf16x8;
typedef __attribute__((ext_vector_type(4))) float f32x4;

__device__ __forceinline__ short to_bf16(float f) {
  __hip_bfloat16 h = __float2bfloat16(f);
  union { __hip_bfloat16 b; short s; } u; u.b = h; return u.s;
}

__device__ __forceinline__ f32x4 mfma16(bf16x8 a, bf16x8 b, f32x4 c) {
  return __builtin_amdgcn_mfma_f32_16x16x32_bf16(a, b, c, 0, 0, 0);
}

__device__ __forceinline__ void gload_lds16(const void* g, void* l) {
  __builtin_amdgcn_global_load_lds(
      (const __attribute__((address_space(1))) unsigned int*)g,
      (__attribute__((address_space(3))) unsigned int*)l,
      16, 0, 0);
}

// ---------------- batched f32 -> bf16 converts ----------------
__global__ __launch_bounds__(256) void cvt3(const float* __restrict__ a,
                                            const float* __restrict__ b,
                                            const float* __restrict__ c,
                                            short* __restrict__ oa,
                                            short* __restrict__ ob,
                                            short* __restrict__ oc) {
  const int z = blockIdx.z;
  const float* x = z == 0 ? a : z == 1 ? b : c;
  short* y = z == 0 ? oa : z == 1 ? ob : oc;
  const int i = (blockIdx.x * 256 + threadIdx.x) * 4;
  const float4 v = *(const float4*)(x + i);
  short4 o;
  o.x = to_bf16(v.x); o.y = to_bf16(v.y); o.z = to_bf16(v.z); o.w = to_bf16(v.w);
  *(short4*)(y + i) = o;
}

__global__ __launch_bounds__(256) void cvt4(const float* __restrict__ a,
                                            const float* __restrict__ b,
                                            const float* __restrict__ c,
                                            const float* __restrict__ d,
                                            short* __restrict__ oa,
                                            short* __restrict__ ob,
                                            short* __restrict__ oc,
                                            short* __restrict__ od) {
  const int z = blockIdx.z;
  const float* x = z == 0 ? a : z == 1 ? b : z == 2 ? c : d;
  short* y = z == 0 ? oa : z == 1 ? ob : z == 2 ? oc : od;
  const int i = (blockIdx.x * 256 + threadIdx.x) * 4;
  const float4 v = *(const float4*)(x + i);
  short4 o;
  o.x = to_bf16(v.x); o.y = to_bf16(v.y); o.z = to_bf16(v.z); o.w = to_bf16(v.w);
  *(short4*)(y + i) = o;
}

// ---------------- batched QKV projection: Y = X * W^T + b, BK=64 ----------
// z=0: Q -> (b,h,s,dk) scaled by 0.125*log2(e);  z=1: K -> (b,h,s,dk);
// z=2: V -> (b,h,dk,s)
__global__ __launch_bounds__(256) void gemm_qkv(const short* __restrict__ Xq,
                                                const short* __restrict__ Xk,
                                                const short* __restrict__ Xv,
                                                const short* __restrict__ Wq,
                                                const short* __restrict__ Wk,
                                                const short* __restrict__ Wv,
                                                const float* __restrict__ bq,
                                                const float* __restrict__ bk,
                                                const float* __restrict__ bv,
                                                short* __restrict__ Qh,
                                                short* __restrict__ Kh,
                                                short* __restrict__ VT) {
  constexpr int K = 1024;
  __shared__ short As[128 * 64];
  __shared__ short Bs[128 * 64];
  const int z = blockIdx.z;
  const short* A    = z == 0 ? Xq : z == 1 ? Xk : Xv;
  const short* Wt   = z == 0 ? Wq : z == 1 ? Wk : Wv;
  const float* bias = z == 0 ? bq : z == 1 ? bk : bv;

  const int tid = threadIdx.x;
  const int w = tid >> 6, lane = tid & 63;
  const int m0 = blockIdx.x * 128, n0 = blockIdx.y * 128;
  const int wm = w >> 1, wn = w & 1;
  const int fr = lane & 15, fg = lane >> 4;
  const int srow = tid >> 3, scol = (tid & 7) * 8;

  f32x4 acc[4][4] = {};

  for (int k0 = 0; k0 < K; k0 += 64) {
    __syncthreads();
#pragma unroll
    for (int i = 0; i < 4; ++i) {
      const int row = i * 32 + srow;
      gload_lds16(A  + (size_t)(m0 + row) * K + k0 + scol, As + row * 64 + scol);
      gload_lds16(Wt + (size_t)(n0 + row) * K + k0 + scol, Bs + row * 64 + scol);
    }
    asm volatile("s_waitcnt vmcnt(0)" ::: "memory");
    __syncthreads();

    bf16x8 af[4][2], bfr[4][2];
#pragma unroll
    for (int i = 0; i < 4; ++i)
#pragma unroll
      for (int hh = 0; hh < 2; ++hh) {
        af[i][hh]  = *(const bf16x8*)(As + (wm * 64 + i * 16 + fr) * 64 + hh * 32 + fg * 8);
        bfr[i][hh] = *(const bf16x8*)(Bs + (wn * 64 + i * 16 + fr) * 64 + hh * 32 + fg * 8);
      }
    __builtin_amdgcn_s_setprio(1);
#pragma unroll
    for (int mi = 0; mi < 4; ++mi)
#pragma unroll
      for (int ni = 0; ni < 4; ++ni) {
        acc[mi][ni] = mfma16(af[mi][0], bfr[ni][0], acc[mi][ni]);
        acc[mi][ni] = mfma16(af[mi][1], bfr[ni][1], acc[mi][ni]);
      }
    __builtin_amdgcn_s_setprio(0);
  }

  const float scale = (z == 0) ? 0.18033688011112042f : 1.0f;  // 0.125*log2(e)
#pragma unroll
  for (int mi = 0; mi < 4; ++mi)
#pragma unroll
    for (int ni = 0; ni < 4; ++ni) {
      const int col = n0 + wn * 64 + ni * 16 + fr;
      const float bval = bias[col];
      const int h = col >> 6, d = col & 63;
#pragma unroll
      for (int r = 0; r < 4; ++r) {
        const int row = m0 + wm * 64 + mi * 16 + fg * 4 + r;
        const float val = (acc[mi][ni][r] + bval) * scale;
        const int b = row >> 11, s = row & (SS - 1);
        if (z < 2) {
          short* dst = (z == 0) ? Qh : Kh;
          dst[((size_t)(b * NH + h) * SS + s) * DK + d] = to_bf16(val);
        } else {
          VT[((size_t)(b * NH + h) * DK + d) * SS + s] = to_bf16(val);
        }
      }
    }
}

// ---------------- O-projection: 128x64 tiles, BK=64, f32 out ----------------
__global__ __launch_bounds__(256) void gemm_out(const short* __restrict__ A,
                                                const short* __restrict__ Wt,
                                                const float* __restrict__ bias,
                                                float* __restrict__ Y) {
  constexpr int K = 1024;
  __shared__ short As[128 * 64];
  __shared__ short Bs[64 * 64];
  const int tid = threadIdx.x;
  const int w = tid >> 6, lane = tid & 63;
  const int m0 = blockIdx.x * 128, n0 = blockIdx.y * 64;
  const int wm = w >> 1, wn = w & 1;
  const int fr = lane & 15, fg = lane >> 4;
  const int srow = tid >> 3, scol = (tid & 7) * 8;

  f32x4 acc[4][2] = {};

  for (int k0 = 0; k0 < K; k0 += 64) {
    __syncthreads();
#pragma unroll
    for (int i = 0; i < 4; ++i) {
      const int row = i * 32 + srow;
      gload_lds16(A + (size_t)(m0 + row) * K + k0 + scol, As + row * 64 + scol);
    }
#pragma unroll
    for (int i = 0; i < 2; ++i) {
      const int row = i * 32 + srow;
      gload_lds16(Wt + (size_t)(n0 + row) * K + k0 + scol, Bs + row * 64 + scol);
    }
    asm volatile("s_waitcnt vmcnt(0)" ::: "memory");
    __syncthreads();

    bf16x8 af[4][2], bfr[2][2];
#pragma unroll
    for (int i = 0; i < 4; ++i)
#pragma unroll
      for (int hh = 0; hh < 2; ++hh)
        af[i][hh] = *(const bf16x8*)(As + (wm * 64 + i * 16 + fr) * 64 + hh * 32 + fg * 8);
#pragma unroll
    for (int i = 0; i < 2; ++i)
#pragma unroll
      for (int hh = 0; hh < 2; ++hh)
        bfr[i][hh] = *(const bf16x8*)(Bs + (wn * 32 + i * 16 + fr) * 64 + hh * 32 + fg * 8);
    __builtin_amdgcn_s_setprio(1);
#pragma unroll
    for (int mi = 0; mi < 4; ++mi)
#pragma unroll
      for (int ni = 0; ni < 2; ++ni) {
        acc[mi][ni] = mfma16(af[mi][0], bfr[ni][0], acc[mi][ni]);
        acc[mi][ni] = mfma16(af[mi][1], bfr[ni][1], acc[mi][ni]);
      }
    __builtin_amdgcn_s_setprio(0);
  }

#pragma unroll
  for (int mi = 0; mi < 4; ++mi)
#pragma unroll
    for (int ni = 0; ni < 2; ++ni) {
      const int col = n0 + wn * 32 + ni * 16 + fr;
      const float bval = bias[col];
#pragma unroll
      for (int r = 0; r < 4; ++r) {
        const int row = m0 + wm * 64 + mi * 16 + fg * 4 + r;
        Y[(size_t)row * D_MODEL + col] = acc[mi][ni][r] + bval;
      }
    }
}

// ---------------- causal flash attention, balanced strip pairs -------------
// Block = two 64-row q-strips of one head processed sequentially: strip j
// (j+1 tiles) then strip 31-j (32-j tiles) -> EXACTLY 33 tiles per block.
// 512 blocks (2/CU, all resident, zero tail). 4 waves x 16 q rows share
// K/V tiles staged via global_load_lds DMA (double-buffered, swizzled).
// Swapped QK^T, exp2 softmax (Q pre-scaled 0.125*log2e), wave-private P_lds,
// MFMA l-sum, defer-max (THR=11 log2 units).
__global__ __launch_bounds__(256) void attn_kernel(const short* __restrict__ Qh,
                                                   const short* __restrict__ Kh,
                                                   const short* __restrict__ VT,
                                                   short* __restrict__ AO) {
  __shared__ short Ks[2][64 * 64];     // [buf][key-row][d], swizzled, 16 KB
  __shared__ short Vs[2][64 * 64];     // [buf][d-row][key], swizzled, 16 KB
  __shared__ short P_lds[4][16 * 64];  // wave-private P^T, 8 KB

  const int tid = threadIdx.x, w = tid >> 6, lane = tid & 63;
  const int fr = lane & 15, fg = lane >> 4;
  const int kr = fg * 4;
  const int swz = (fr & 7) << 4;

  // XCD swizzle: 512 blocks, 64 consecutive lids per XCD -> 4 heads/XCD
  const int bid = blockIdx.x;
  const int lid = ((bid & 7) << 6) | (bid >> 3);
  const int bh = lid >> 4;      // 0..31
  const int j = lid & 15;       // pair index: strips {j, 31-j}
  const int b = bh >> 4, h = bh & 15;

  const short* Qp = Qh + (size_t)bh * SS * DK;
  const short* Kp = Kh + (size_t)bh * SS * DK;
  const short* Vp = VT + (size_t)bh * DK * SS;

  // staging decomposition: 256 threads x 16B x 2 passes = 8KB per tile
  const int sc_c = tid & 7;    // 16B chunk within 128B row
  const int sc_r = tid >> 3;   // row 0..31 (pass adds 32)

  const int T0 = j + 1;        // segment-0 tiles; segment-1 = 32-j; total 33

  int qw = j * 64 + w * 16;    // wave's q base (segment 0)
  bf16x8 qf[2];
#pragma unroll
  for (int hh = 0; hh < 2; ++hh)
    qf[hh] = *(const bf16x8*)(Qp + (size_t)(qw + fr) * DK + hh * 32 + fg * 8);

  // ones A-fragment (row 0 of the l-sum tile = 1.0, rest 0)
  const short onev = (fr == 0) ? (short)0x3F80 : (short)0;
  const bf16x8 af4 = {onev, onev, onev, onev, onev, onev, onev, onev};

  f32x4 o[5] = {};  // d-tiles 0..3 + l-sum; lane holds O^T[d=t*16+kr+r][q=fr]
  float m_run = -1e30f;

#define STAGE_KV(buf, kk0)                                                    \
  do {                                                                        \
    _Pragma("unroll") for (int p = 0; p < 2; ++p) {                           \
      const int row = p * 32 + sc_r;                                          \
      const int sc = sc_c ^ (row & 7);                                        \
      gload_lds16(Kp + (size_t)((kk0) + row) * DK + sc * 8,                   \
                  &Ks[buf][row * 64 + sc_c * 8]);                             \
      gload_lds16(Vp + (size_t)row * SS + (kk0) + sc * 8,                     \
                  &Vs[buf][row * 64 + sc_c * 8]);                             \
    }                                                                         \
  } while (0)

  STAGE_KV(0, 0);
  asm volatile("s_waitcnt vmcnt(0)" ::: "memory");
  __syncthreads();

  for (int g = 0; g < 33; ++g) {
    const int cur = g & 1;
    if (g + 1 < 33) {
      const int nk0 = (g + 1 < T0) ? (g + 1) * 64 : (g + 1 - T0) * 64;
      STAGE_KV(cur ^ 1, nk0);  // DMA overlaps compute
    }

    const char* KsB = (const char*)Ks[cur];
    const char* VsB = (const char*)Vs[cur];

    // QK^T: st[kt][r] = S^T[kk = kt*16+kr+r][q = fr]
    f32x4 st[4];
    __builtin_amdgcn_s_setprio(1);
#pragma unroll
    for (int kt = 0; kt < 4; ++kt) {
      const bf16x8 k0f = *(const bf16x8*)(KsB + (kt * 16 + fr) * 128 + ((fg * 16) ^ swz));
      const bf16x8 k1f = *(const bf16x8*)(KsB + (kt * 16 + fr) * 128 + ((64 + fg * 16) ^ swz));
      f32x4 z = {};
      z = mfma16(k0f, qf[0], z);
      z = mfma16(k1f, qf[1], z);
      st[kt] = z;
    }
    __builtin_amdgcn_s_setprio(0);

    // diagonal tile of either segment: mask kk > q (within-block offsets)
    if (g == T0 - 1 || g == 32) {
#pragma unroll
      for (int kt = 0; kt < 4; ++kt)
#pragma unroll
        for (int r = 0; r < 4; ++r)
          if (kt * 16 + kr + r > w * 16 + fr) st[kt][r] = -1e30f;
    }

    float pmax = st[0][0];
#pragma unroll
    for (int kt = 0; kt < 4; ++kt)
#pragma unroll
      for (int r = 0; r < 4; ++r) pmax = fmaxf(pmax, st[kt][r]);
    pmax = fmaxf(pmax, __shfl_xor(pmax, 16));
    pmax = fmaxf(pmax, __shfl_xor(pmax, 32));

    if (!__all(pmax <= m_run + 11.0f)) {
      const float mn = fmaxf(m_run, pmax);
      const float al = __builtin_amdgcn_exp2f(m_run - mn);
      m_run = mn;
#pragma unroll
      for (int t = 0; t < 5; ++t)
#pragma unroll
        for (int r = 0; r < 4; ++r) o[t][r] *= al;
    }

    // P^T -> wave-private LDS (row q=fr, swizzled), packed 8B writes
    {
      char* base = (char*)P_lds[w];
#pragma unroll
      for (int kt = 0; kt < 4; ++kt) {
        short4 sv;
        sv.x = to_bf16(__builtin_amdgcn_exp2f(st[kt][0] - m_run));
        sv.y = to_bf16(__builtin_amdgcn_exp2f(st[kt][1] - m_run));
        sv.z = to_bf16(__builtin_amdgcn_exp2f(st[kt][2] - m_run));
        sv.w = to_bf16(__builtin_amdgcn_exp2f(st[kt][3] - m_run));
        *(short4*)(base + ((fr * 128 + kt * 32 + fg * 8) ^ swz)) = sv;
      }
    }
    asm volatile("s_waitcnt lgkmcnt(0)" ::: "memory");

    // PV: O^T[d][q] += V^T[d][kk] * P^T[kk][q], V from swizzled LDS
    __builtin_amdgcn_s_setprio(1);
#pragma unroll
    for (int c = 0; c < 2; ++c) {
      const bf16x8 pf = *(const bf16x8*)((const char*)P_lds[w] +
                                         ((fr * 128 + c * 64 + fg * 16) ^ swz));
#pragma unroll
      for (int t = 0; t < 4; ++t) {
        const bf16x8 vfb = *(const bf16x8*)(VsB + (t * 16 + fr) * 128 +
                                            ((c * 64 + fg * 16) ^ swz));
        o[t] = mfma16(vfb, pf, o[t]);
      }
      o[4] = mfma16(af4, pf, o[4]);
    }
    __builtin_amdgcn_s_setprio(0);

    asm volatile("s_waitcnt vmcnt(0)" ::: "memory");
    __syncthreads();

    // segment switch: store strip-j output, reset state, load strip-(31-j) Q
    if (g == T0 - 1) {
      const float l = __shfl(o[4][0], fr);
      const float inv = 1.0f / l;
      const int s = qw + fr;
#pragma unroll
      for (int t = 0; t < 4; ++t) {
        short4 ov = {to_bf16(o[t][0] * inv), to_bf16(o[t][1] * inv),
                     to_bf16(o[t][2] * inv), to_bf16(o[t][3] * inv)};
        *(short4*)(AO + (size_t)(b * SS + s) * D_MODEL + h * 64 + t * 16 + kr) = ov;
      }
#pragma unroll
      for (int t = 0; t < 5; ++t)
#pragma unroll
        for (int r = 0; r < 4; ++r) o[t][r] = 0.f;
      m_run = -1e30f;
      qw = (31 - j) * 64 + w * 16;
#pragma unroll
      for (int hh = 0; hh < 2; ++hh)
        qf[hh] = *(const bf16x8*)(Qp + (size_t)(qw + fr) * DK + hh * 32 + fg * 8);
    }
  }
#undef STAGE_KV

  // epilogue segment 1: l on row 0 (lanes 0..15) of o[4]; broadcast by shfl
  const float l = __shfl(o[4][0], fr);
  const float inv = 1.0f / l;
  const int s = qw + fr;
#pragma unroll
  for (int t = 0; t < 4; ++t) {
    short4 ov = {to_bf16(o[t][0] * inv), to_bf16(o[t][1] * inv),
                 to_bf16(o[t][2] * inv), to_bf16(o[t][3] * inv)};
    *(short4*)(AO + (size_t)(b * SS + s) * D_MODEL + h * 64 + t * 16 + kr) = ov;
  }
}

extern "C" void kernel_launch(void* const* d_in, const int* in_sizes, int n_in,
                              void* d_out, int out_size, void* d_ws, size_t ws_size,
                              hipStream_t stream) {
  const float* q  = (const float*)d_in[0];
  const float* k  = (const float*)d_in[1];
  const float* v  = (const float*)d_in[2];
  const float* Wq = (const float*)d_in[4];
  const float* bq = (const float*)d_in[5];
  const float* Wk = (const float*)d_in[6];
  const float* bk = (const float*)d_in[7];
  const float* Wv = (const float*)d_in[8];
  const float* bv = (const float*)d_in[9];
  const float* Wo = (const float*)d_in[10];
  const float* bo = (const float*)d_in[11];

  char* ws = (char*)d_ws;
  const size_t MB = 1u << 20;
  short* Xq = (short*)(ws + 0 * MB);
  short* Xk = (short*)(ws + 8 * MB);
  short* Xv = (short*)(ws + 16 * MB);
  short* Bq = (short*)(ws + 24 * MB);
  short* Bk = (short*)(ws + 26 * MB);
  short* Bv = (short*)(ws + 28 * MB);
  short* Bo = (short*)(ws + 30 * MB);
  short* Qh = (short*)(ws + 32 * MB);
  short* Kh = (short*)(ws + 40 * MB);
  short* VT = (short*)(ws + 48 * MB);
  short* AO = (short*)(ws + 56 * MB);

  cvt3<<<dim3(MROWS * D_MODEL / 1024, 1, 3), 256, 0, stream>>>(q, k, v, Xq, Xk, Xv);
  cvt4<<<dim3(D_MODEL * D_MODEL / 1024, 1, 4), 256, 0, stream>>>(Wq, Wk, Wv, Wo, Bq, Bk, Bv, Bo);

  gemm_qkv<<<dim3(MROWS / 128, D_MODEL / 128, 3), 256, 0, stream>>>(
      Xq, Xk, Xv, Bq, Bk, Bv, bq, bk, bv, Qh, Kh, VT);

  attn_kernel<<<dim3(512), 256, 0, stream>>>(Qh, Kh, VT, AO);

  gemm_out<<<dim3(MROWS / 128, D_MODEL / 64), 256, 0, stream>>>(AO, Bo, bo, (float*)d_out);
}

// Round 8
// 123.726 us; speedup vs baseline: 1.1993x; 1.0196x over previous
//
#include <hip/hip_runtime.h>
#include <hip/hip_bf16.h>
#include <stdint.h>

#define D_MODEL 1024
#define NH 16
#define DK 64
#define BB 2
#define SS 2048
#define MROWS (BB*SS)  // 4096

typedef __attribute__((ext_vector_type(8))) short bf16x8;
typedef __attribute__((ext_vector_type(4))) float f32x4;

__device__ __forceinline__ short to_bf16(float f) {
  __hip_bfloat16 h = __float2bfloat16(f);
  union { __hip_bfloat16 b; short s; } u; u.b = h; return u.s;
}

__device__ __forceinline__ f32x4 mfma16(bf16x8 a, bf16x8 b, f32x4 c) {
  return __builtin_amdgcn_mfma_f32_16x16x32_bf16(a, b, c, 0, 0, 0);
}

__device__ __forceinline__ void gload_lds16(const void* g, void* l) {
  __builtin_amdgcn_global_load_lds(
      (const __attribute__((address_space(1))) unsigned int*)g,
      (__attribute__((address_space(3))) unsigned int*)l,
      16, 0, 0);
}

__device__ __forceinline__ float max3f(float a, float b, float c) {
  return fmaxf(fmaxf(a, b), c);  // clang fuses to v_max3_f32
}

// ---------------- batched f32 -> bf16 converts ----------------
__global__ __launch_bounds__(256) void cvt3(const float* __restrict__ a,
                                            const float* __restrict__ b,
                                            const float* __restrict__ c,
                                            short* __restrict__ oa,
                                            short* __restrict__ ob,
                                            short* __restrict__ oc) {
  const int z = blockIdx.z;
  const float* x = z == 0 ? a : z == 1 ? b : c;
  short* y = z == 0 ? oa : z == 1 ? ob : oc;
  const int i = (blockIdx.x * 256 + threadIdx.x) * 4;
  const float4 v = *(const float4*)(x + i);
  short4 o;
  o.x = to_bf16(v.x); o.y = to_bf16(v.y); o.z = to_bf16(v.z); o.w = to_bf16(v.w);
  *(short4*)(y + i) = o;
}

__global__ __launch_bounds__(256) void cvt4(const float* __restrict__ a,
                                            const float* __restrict__ b,
                                            const float* __restrict__ c,
                                            const float* __restrict__ d,
                                            short* __restrict__ oa,
                                            short* __restrict__ ob,
                                            short* __restrict__ oc,
                                            short* __restrict__ od) {
  const int z = blockIdx.z;
  const float* x = z == 0 ? a : z == 1 ? b : z == 2 ? c : d;
  short* y = z == 0 ? oa : z == 1 ? ob : z == 2 ? oc : od;
  const int i = (blockIdx.x * 256 + threadIdx.x) * 4;
  const float4 v = *(const float4*)(x + i);
  short4 o;
  o.x = to_bf16(v.x); o.y = to_bf16(v.y); o.z = to_bf16(v.z); o.w = to_bf16(v.w);
  *(short4*)(y + i) = o;
}

// ---------------- batched QKV projection: Y = X * W^T + b, BK=64 ----------
// z=0: Q -> (b,h,s,dk) scaled by 0.125*log2(e);  z=1: K -> (b,h,s,dk);
// z=2: V -> (b,h,dk,s)
__global__ __launch_bounds__(256) void gemm_qkv(const short* __restrict__ Xq,
                                                const short* __restrict__ Xk,
                                                const short* __restrict__ Xv,
                                                const short* __restrict__ Wq,
                                                const short* __restrict__ Wk,
                                                const short* __restrict__ Wv,
                                                const float* __restrict__ bq,
                                                const float* __restrict__ bk,
                                                const float* __restrict__ bv,
                                                short* __restrict__ Qh,
                                                short* __restrict__ Kh,
                                                short* __restrict__ VT) {
  constexpr int K = 1024;
  __shared__ short As[128 * 64];
  __shared__ short Bs[128 * 64];
  const int z = blockIdx.z;
  const short* A    = z == 0 ? Xq : z == 1 ? Xk : Xv;
  const short* Wt   = z == 0 ? Wq : z == 1 ? Wk : Wv;
  const float* bias = z == 0 ? bq : z == 1 ? bk : bv;

  const int tid = threadIdx.x;
  const int w = tid >> 6, lane = tid & 63;
  const int m0 = blockIdx.x * 128, n0 = blockIdx.y * 128;
  const int wm = w >> 1, wn = w & 1;
  const int fr = lane & 15, fg = lane >> 4;
  const int srow = tid >> 3, scol = (tid & 7) * 8;

  f32x4 acc[4][4] = {};

  for (int k0 = 0; k0 < K; k0 += 64) {
    __syncthreads();
#pragma unroll
    for (int i = 0; i < 4; ++i) {
      const int row = i * 32 + srow;
      gload_lds16(A  + (size_t)(m0 + row) * K + k0 + scol, As + row * 64 + scol);
      gload_lds16(Wt + (size_t)(n0 + row) * K + k0 + scol, Bs + row * 64 + scol);
    }
    asm volatile("s_waitcnt vmcnt(0)" ::: "memory");
    __syncthreads();

    bf16x8 af[4][2], bfr[4][2];
#pragma unroll
    for (int i = 0; i < 4; ++i)
#pragma unroll
      for (int hh = 0; hh < 2; ++hh) {
        af[i][hh]  = *(const bf16x8*)(As + (wm * 64 + i * 16 + fr) * 64 + hh * 32 + fg * 8);
        bfr[i][hh] = *(const bf16x8*)(Bs + (wn * 64 + i * 16 + fr) * 64 + hh * 32 + fg * 8);
      }
    __builtin_amdgcn_s_setprio(1);
#pragma unroll
    for (int mi = 0; mi < 4; ++mi)
#pragma unroll
      for (int ni = 0; ni < 4; ++ni) {
        acc[mi][ni] = mfma16(af[mi][0], bfr[ni][0], acc[mi][ni]);
        acc[mi][ni] = mfma16(af[mi][1], bfr[ni][1], acc[mi][ni]);
      }
    __builtin_amdgcn_s_setprio(0);
  }

  const float scale = (z == 0) ? 0.18033688011112042f : 1.0f;  // 0.125*log2(e)
#pragma unroll
  for (int mi = 0; mi < 4; ++mi)
#pragma unroll
    for (int ni = 0; ni < 4; ++ni) {
      const int col = n0 + wn * 64 + ni * 16 + fr;
      const float bval = bias[col];
      const int h = col >> 6, d = col & 63;
#pragma unroll
      for (int r = 0; r < 4; ++r) {
        const int row = m0 + wm * 64 + mi * 16 + fg * 4 + r;
        const float val = (acc[mi][ni][r] + bval) * scale;
        const int b = row >> 11, s = row & (SS - 1);
        if (z < 2) {
          short* dst = (z == 0) ? Qh : Kh;
          dst[((size_t)(b * NH + h) * SS + s) * DK + d] = to_bf16(val);
        } else {
          VT[((size_t)(b * NH + h) * DK + d) * SS + s] = to_bf16(val);
        }
      }
    }
}

// ---------------- O-projection: 128x64 tiles, BK=64, f32 out ----------------
__global__ __launch_bounds__(256) void gemm_out(const short* __restrict__ A,
                                                const short* __restrict__ Wt,
                                                const float* __restrict__ bias,
                                                float* __restrict__ Y) {
  constexpr int K = 1024;
  __shared__ short As[128 * 64];
  __shared__ short Bs[64 * 64];
  const int tid = threadIdx.x;
  const int w = tid >> 6, lane = tid & 63;
  const int m0 = blockIdx.x * 128, n0 = blockIdx.y * 64;
  const int wm = w >> 1, wn = w & 1;
  const int fr = lane & 15, fg = lane >> 4;
  const int srow = tid >> 3, scol = (tid & 7) * 8;

  f32x4 acc[4][2] = {};

  for (int k0 = 0; k0 < K; k0 += 64) {
    __syncthreads();
#pragma unroll
    for (int i = 0; i < 4; ++i) {
      const int row = i * 32 + srow;
      gload_lds16(A + (size_t)(m0 + row) * K + k0 + scol, As + row * 64 + scol);
    }
#pragma unroll
    for (int i = 0; i < 2; ++i) {
      const int row = i * 32 + srow;
      gload_lds16(Wt + (size_t)(n0 + row) * K + k0 + scol, Bs + row * 64 + scol);
    }
    asm volatile("s_waitcnt vmcnt(0)" ::: "memory");
    __syncthreads();

    bf16x8 af[4][2], bfr[2][2];
#pragma unroll
    for (int i = 0; i < 4; ++i)
#pragma unroll
      for (int hh = 0; hh < 2; ++hh)
        af[i][hh] = *(const bf16x8*)(As + (wm * 64 + i * 16 + fr) * 64 + hh * 32 + fg * 8);
#pragma unroll
    for (int i = 0; i < 2; ++i)
#pragma unroll
      for (int hh = 0; hh < 2; ++hh)
        bfr[i][hh] = *(const bf16x8*)(Bs + (wn * 32 + i * 16 + fr) * 64 + hh * 32 + fg * 8);
    __builtin_amdgcn_s_setprio(1);
#pragma unroll
    for (int mi = 0; mi < 4; ++mi)
#pragma unroll
      for (int ni = 0; ni < 2; ++ni) {
        acc[mi][ni] = mfma16(af[mi][0], bfr[ni][0], acc[mi][ni]);
        acc[mi][ni] = mfma16(af[mi][1], bfr[ni][1], acc[mi][ni]);
      }
    __builtin_amdgcn_s_setprio(0);
  }

#pragma unroll
  for (int mi = 0; mi < 4; ++mi)
#pragma unroll
    for (int ni = 0; ni < 2; ++ni) {
      const int col = n0 + wn * 32 + ni * 16 + fr;
      const float bval = bias[col];
#pragma unroll
      for (int r = 0; r < 4; ++r) {
        const int row = m0 + wm * 64 + mi * 16 + fg * 4 + r;
        Y[(size_t)row * D_MODEL + col] = acc[mi][ni][r] + bval;
      }
    }
}

// ---------------- causal flash attention, pipelined balanced pairs ---------
// Block = strips {j, 31-j} sequential (33 tiles exactly); 512 blocks; 4 waves
// x 16 q rows. Deferred-softmax pipeline: body(g) = QK(g) MFMA (matrix pipe)
// || softmax(g-1)+PV(g-1) (VALU pipe), then vmcnt(0)+barrier, then stage(g+2)
// into triple-buffered K/V LDS (DMA has a full iteration in flight).
__global__ __launch_bounds__(256) void attn_kernel(const short* __restrict__ Qh,
                                                   const short* __restrict__ Kh,
                                                   const short* __restrict__ VT,
                                                   short* __restrict__ AO) {
  __shared__ short Ks[3][64 * 64];     // [buf][key-row][d], swizzled, 24 KB
  __shared__ short Vs[3][64 * 64];     // [buf][d-row][key], swizzled, 24 KB
  __shared__ short P_lds[4][16 * 64];  // wave-private P^T, 8 KB

  const int tid = threadIdx.x, w = tid >> 6, lane = tid & 63;
  const int fr = lane & 15, fg = lane >> 4;
  const int kr = fg * 4;
  const int swz = (fr & 7) << 4;

  // XCD swizzle: 512 blocks, 64 consecutive lids per XCD -> 4 heads/XCD
  const int bid = blockIdx.x;
  const int lid = ((bid & 7) << 6) | (bid >> 3);
  const int bh = lid >> 4;      // 0..31
  const int j = lid & 15;       // pair index: strips {j, 31-j}
  const int b = bh >> 4, h = bh & 15;

  const short* Qp = Qh + (size_t)bh * SS * DK;
  const short* Kp = Kh + (size_t)bh * SS * DK;
  const short* Vp = VT + (size_t)bh * DK * SS;

  // staging decomposition: 256 threads x 16B x 2 passes = 8KB per tile
  const int sc_c = tid & 7;    // 16B chunk within 128B row
  const int sc_r = tid >> 3;   // row 0..31 (pass adds 32)

  const int T0 = j + 1;        // segment-0 tiles; segment-1 = 32-j; total 33

  bf16x8 qf[2];
#pragma unroll
  for (int hh = 0; hh < 2; ++hh)
    qf[hh] = *(const bf16x8*)(Qp + (size_t)(j * 64 + w * 16 + fr) * DK + hh * 32 + fg * 8);

  // ones A-fragment (row 0 of the l-sum tile = 1.0, rest 0)
  const short onev = (fr == 0) ? (short)0x3F80 : (short)0;
  const bf16x8 af4 = {onev, onev, onev, onev, onev, onev, onev, onev};

  f32x4 o[5] = {};  // d-tiles 0..3 + l-sum; lane holds O^T[d=t*16+kr+r][q=fr]
  float m_run = -1e30f;
  f32x4 stA[4], stB[4];

#define KK0(g) ((((g) < T0) ? (g) : ((g) - T0)) * 64)
#define STAGE_KV(buf, kk0)                                                    \
  do {                                                                        \
    _Pragma("unroll") for (int p = 0; p < 2; ++p) {                           \
      const int row = p * 32 + sc_r;                                          \
      const int sc = sc_c ^ (row & 7);                                        \
      gload_lds16(Kp + (size_t)((kk0) + row) * DK + sc * 8,                   \
                  &Ks[buf][row * 64 + sc_c * 8]);                             \
      gload_lds16(Vp + (size_t)row * SS + (kk0) + sc * 8,                     \
                  &Vs[buf][row * 64 + sc_c * 8]);                             \
    }                                                                         \
  } while (0)

  // softmax(prev) + PV(prev): consumes stB, buffer bufPrev
  auto softmax_pv = [&](int bufPrev) {
    // row-max via max3 tree (15 values + running)
    float p0 = max3f(stB[0][0], stB[0][1], stB[0][2]);
    float p1 = max3f(stB[0][3], stB[1][0], stB[1][1]);
    float p2 = max3f(stB[1][2], stB[1][3], stB[2][0]);
    float p3 = max3f(stB[2][1], stB[2][2], stB[2][3]);
    float p4 = max3f(stB[3][0], stB[3][1], stB[3][2]);
    float pmax = fmaxf(max3f(p0, p1, p2), max3f(p3, p4, stB[3][3]));
    pmax = fmaxf(pmax, __shfl_xor(pmax, 16));
    pmax = fmaxf(pmax, __shfl_xor(pmax, 32));

    if (!__all(pmax <= m_run + 11.0f)) {
      const float mn = fmaxf(m_run, pmax);
      const float al = __builtin_amdgcn_exp2f(m_run - mn);
      m_run = mn;
#pragma unroll
      for (int t = 0; t < 5; ++t)
#pragma unroll
        for (int r = 0; r < 4; ++r) o[t][r] *= al;
    }

    // P^T -> wave-private LDS (row q=fr, swizzled), packed 8B writes
    char* base = (char*)P_lds[w];
#pragma unroll
    for (int kt = 0; kt < 4; ++kt) {
      short4 sv;
      sv.x = to_bf16(__builtin_amdgcn_exp2f(stB[kt][0] - m_run));
      sv.y = to_bf16(__builtin_amdgcn_exp2f(stB[kt][1] - m_run));
      sv.z = to_bf16(__builtin_amdgcn_exp2f(stB[kt][2] - m_run));
      sv.w = to_bf16(__builtin_amdgcn_exp2f(stB[kt][3] - m_run));
      *(short4*)(base + ((fr * 128 + kt * 32 + fg * 8) ^ swz)) = sv;
    }
    asm volatile("s_waitcnt lgkmcnt(0)" ::: "memory");

    const char* VsB = (const char*)Vs[bufPrev];
    __builtin_amdgcn_s_setprio(1);
#pragma unroll
    for (int c = 0; c < 2; ++c) {
      const bf16x8 pf = *(const bf16x8*)((const char*)P_lds[w] +
                                         ((fr * 128 + c * 64 + fg * 16) ^ swz));
#pragma unroll
      for (int t = 0; t < 4; ++t) {
        const bf16x8 vfb = *(const bf16x8*)(VsB + (t * 16 + fr) * 128 +
                                            ((c * 64 + fg * 16) ^ swz));
        o[t] = mfma16(vfb, pf, o[t]);
      }
      o[4] = mfma16(af4, pf, o[4]);
    }
    __builtin_amdgcn_s_setprio(0);
  };

  auto store_o = [&](int qbase) {
    const float l = __shfl(o[4][0], fr);
    const float inv = 1.0f / l;
    const int s = qbase + w * 16 + fr;
#pragma unroll
    for (int t = 0; t < 4; ++t) {
      short4 ov = {to_bf16(o[t][0] * inv), to_bf16(o[t][1] * inv),
                   to_bf16(o[t][2] * inv), to_bf16(o[t][3] * inv)};
      *(short4*)(AO + (size_t)(b * SS + s) * D_MODEL + h * 64 + t * 16 + kr) = ov;
    }
  };

  // prologue: stage tiles 0 and 1
  STAGE_KV(0, 0);
  STAGE_KV(1, KK0(1));
  asm volatile("s_waitcnt vmcnt(0)" ::: "memory");
  __syncthreads();

  for (int g = 0; g < 33; ++g) {
    if (g == T0) {  // segment-1 Q (QK(g) below is segment 1's first tile)
#pragma unroll
      for (int hh = 0; hh < 2; ++hh)
        qf[hh] = *(const bf16x8*)(Qp + (size_t)((31 - j) * 64 + w * 16 + fr) * DK + hh * 32 + fg * 8);
    }

    // QK(g): matrix pipe, overlaps the softmax VALU below
    {
      const char* KsB = (const char*)Ks[g % 3];
      __builtin_amdgcn_s_setprio(1);
#pragma unroll
      for (int kt = 0; kt < 4; ++kt) {
        const bf16x8 k0f = *(const bf16x8*)(KsB + (kt * 16 + fr) * 128 + ((fg * 16) ^ swz));
        const bf16x8 k1f = *(const bf16x8*)(KsB + (kt * 16 + fr) * 128 + ((64 + fg * 16) ^ swz));
        f32x4 z = {};
        z = mfma16(k0f, qf[0], z);
        z = mfma16(k1f, qf[1], z);
        stA[kt] = z;
      }
      __builtin_amdgcn_s_setprio(0);
    }
    if (g == T0 - 1 || g == 32) {  // diagonal tiles: mask kk > q
#pragma unroll
      for (int kt = 0; kt < 4; ++kt)
#pragma unroll
        for (int r = 0; r < 4; ++r)
          if (kt * 16 + kr + r > w * 16 + fr) stA[kt][r] = -1e30f;
    }

    if (g > 0) {
      softmax_pv((g - 1) % 3);
      if (g == T0) {  // segment-0 finished: store + reset
        store_o(j * 64);
#pragma unroll
        for (int t = 0; t < 5; ++t)
#pragma unroll
          for (int r = 0; r < 4; ++r) o[t][r] = 0.f;
        m_run = -1e30f;
      }
    }

#pragma unroll
    for (int kt = 0; kt < 4; ++kt) stB[kt] = stA[kt];

    asm volatile("s_waitcnt vmcnt(0)" ::: "memory");
    __syncthreads();
    if (g + 2 <= 32) STAGE_KV((g + 2) % 3, KK0(g + 2));
  }

  // epilogue: softmax+PV of tile 32, store segment 1
  softmax_pv(32 % 3);
  store_o((31 - j) * 64);
#undef STAGE_KV
#undef KK0
}

extern "C" void kernel_launch(void* const* d_in, const int* in_sizes, int n_in,
                              void* d_out, int out_size, void* d_ws, size_t ws_size,
                              hipStream_t stream) {
  const float* q  = (const float*)d_in[0];
  const float* k  = (const float*)d_in[1];
  const float* v  = (const float*)d_in[2];
  const float* Wq = (const float*)d_in[4];
  const float* bq = (const float*)d_in[5];
  const float* Wk = (const float*)d_in[6];
  const float* bk = (const float*)d_in[7];
  const float* Wv = (const float*)d_in[8];
  const float* bv = (const float*)d_in[9];
  const float* Wo = (const float*)d_in[10];
  const float* bo = (const float*)d_in[11];

  char* ws = (char*)d_ws;
  const size_t MB = 1u << 20;
  short* Xq = (short*)(ws + 0 * MB);
  short* Xk = (short*)(ws + 8 * MB);
  short* Xv = (short*)(ws + 16 * MB);
  short* Bq = (short*)(ws + 24 * MB);
  short* Bk = (short*)(ws + 26 * MB);
  short* Bv = (short*)(ws + 28 * MB);
  short* Bo = (short*)(ws + 30 * MB);
  short* Qh = (short*)(ws + 32 * MB);
  short* Kh = (short*)(ws + 40 * MB);
  short* VT = (short*)(ws + 48 * MB);
  short* AO = (short*)(ws + 56 * MB);

  cvt3<<<dim3(MROWS * D_MODEL / 1024, 1, 3), 256, 0, stream>>>(q, k, v, Xq, Xk, Xv);
  cvt4<<<dim3(D_MODEL * D_MODEL / 1024, 1, 4), 256, 0, stream>>>(Wq, Wk, Wv, Wo, Bq, Bk, Bv, Bo);

  gemm_qkv<<<dim3(MROWS / 128, D_MODEL / 128, 3), 256, 0, stream>>>(
      Xq, Xk, Xv, Bq, Bk, Bv, bq, bk, bv, Qh, Kh, VT);

  attn_kernel<<<dim3(512), 256, 0, stream>>>(Qh, Kh, VT, AO);

  gemm_out<<<dim3(MROWS / 128, D_MODEL / 64), 256, 0, stream>>>(AO, Bo, bo, (float*)d_out);
}

// Round 9
// 123.170 us; speedup vs baseline: 1.2047x; 1.0045x over previous
//
#include <hip/hip_runtime.h>
#include <hip/hip_bf16.h>
#include <stdint.h>

#define D_MODEL 1024
#define NH 16
#define DK 64
#define BB 2
#define SS 2048
#define MROWS (BB*SS)  // 4096

typedef __attribute__((ext_vector_type(8))) short bf16x8;
typedef __attribute__((ext_vector_type(4))) float f32x4;

__device__ __forceinline__ short to_bf16(float f) {
  __hip_bfloat16 h = __float2bfloat16(f);
  union { __hip_bfloat16 b; short s; } u; u.b = h; return u.s;
}

__device__ __forceinline__ f32x4 mfma16(bf16x8 a, bf16x8 b, f32x4 c) {
  return __builtin_amdgcn_mfma_f32_16x16x32_bf16(a, b, c, 0, 0, 0);
}

__device__ __forceinline__ void gload_lds16(const void* g, void* l) {
  __builtin_amdgcn_global_load_lds(
      (const __attribute__((address_space(1))) unsigned int*)g,
      (__attribute__((address_space(3))) unsigned int*)l,
      16, 0, 0);
}

__device__ __forceinline__ float max3f(float a, float b, float c) {
  return fmaxf(fmaxf(a, b), c);  // clang fuses to v_max3_f32
}

// ---------------- batched f32 -> bf16 converts ----------------
__global__ __launch_bounds__(256) void cvt3(const float* __restrict__ a,
                                            const float* __restrict__ b,
                                            const float* __restrict__ c,
                                            short* __restrict__ oa,
                                            short* __restrict__ ob,
                                            short* __restrict__ oc) {
  const int z = blockIdx.z;
  const float* x = z == 0 ? a : z == 1 ? b : c;
  short* y = z == 0 ? oa : z == 1 ? ob : oc;
  const int i = (blockIdx.x * 256 + threadIdx.x) * 4;
  const float4 v = *(const float4*)(x + i);
  short4 o;
  o.x = to_bf16(v.x); o.y = to_bf16(v.y); o.z = to_bf16(v.z); o.w = to_bf16(v.w);
  *(short4*)(y + i) = o;
}

__global__ __launch_bounds__(256) void cvt4(const float* __restrict__ a,
                                            const float* __restrict__ b,
                                            const float* __restrict__ c,
                                            const float* __restrict__ d,
                                            short* __restrict__ oa,
                                            short* __restrict__ ob,
                                            short* __restrict__ oc,
                                            short* __restrict__ od) {
  const int z = blockIdx.z;
  const float* x = z == 0 ? a : z == 1 ? b : z == 2 ? c : d;
  short* y = z == 0 ? oa : z == 1 ? ob : z == 2 ? oc : od;
  const int i = (blockIdx.x * 256 + threadIdx.x) * 4;
  const float4 v = *(const float4*)(x + i);
  short4 o;
  o.x = to_bf16(v.x); o.y = to_bf16(v.y); o.z = to_bf16(v.z); o.w = to_bf16(v.w);
  *(short4*)(y + i) = o;
}

// ---------------- batched QKV projection: Y = X * W^T + b ------------------
// BK=32, double-buffered LDS, stage-ahead (DMA for step t+1 issued before
// compute of step t; vmcnt(0) only at the buffer-swap barrier).
// z=0: Q -> (b,h,s,dk) scaled by 0.125*log2(e);  z=1: K -> (b,h,s,dk);
// z=2: V -> (b,h,dk,s)
__global__ __launch_bounds__(256) void gemm_qkv(const short* __restrict__ Xq,
                                                const short* __restrict__ Xk,
                                                const short* __restrict__ Xv,
                                                const short* __restrict__ Wq,
                                                const short* __restrict__ Wk,
                                                const short* __restrict__ Wv,
                                                const float* __restrict__ bq,
                                                const float* __restrict__ bk,
                                                const float* __restrict__ bv,
                                                short* __restrict__ Qh,
                                                short* __restrict__ Kh,
                                                short* __restrict__ VT) {
  constexpr int K = 1024, NSTEP = K / 32;
  __shared__ short As[2][128 * 32];
  __shared__ short Bs[2][128 * 32];
  const int z = blockIdx.z;
  const short* A    = z == 0 ? Xq : z == 1 ? Xk : Xv;
  const short* Wt   = z == 0 ? Wq : z == 1 ? Wk : Wv;
  const float* bias = z == 0 ? bq : z == 1 ? bk : bv;

  const int tid = threadIdx.x;
  const int w = tid >> 6, lane = tid & 63;
  const int m0 = blockIdx.x * 128, n0 = blockIdx.y * 128;
  const int wm = w >> 1, wn = w & 1;
  const int fr = lane & 15, fg = lane >> 4;
  const int srow = tid >> 2, scol = (tid & 3) * 8;

  f32x4 acc[4][4] = {};

#define QKV_STAGE(buf, k0)                                                    \
  do {                                                                        \
    _Pragma("unroll") for (int i = 0; i < 2; ++i) {                           \
      const int row = i * 64 + srow;                                          \
      gload_lds16(A  + (size_t)(m0 + row) * K + (k0) + scol,                  \
                  &As[buf][row * 32 + scol]);                                 \
      gload_lds16(Wt + (size_t)(n0 + row) * K + (k0) + scol,                  \
                  &Bs[buf][row * 32 + scol]);                                 \
    }                                                                         \
  } while (0)

  QKV_STAGE(0, 0);
  asm volatile("s_waitcnt vmcnt(0)" ::: "memory");
  __syncthreads();

  for (int t = 0; t < NSTEP; ++t) {
    const int cur = t & 1;
    if (t + 1 < NSTEP) QKV_STAGE(cur ^ 1, (t + 1) * 32);  // DMA overlaps compute

    bf16x8 af[4], bfr[4];
#pragma unroll
    for (int i = 0; i < 4; ++i) {
      af[i]  = *(const bf16x8*)(&As[cur][(wm * 64 + i * 16 + fr) * 32 + fg * 8]);
      bfr[i] = *(const bf16x8*)(&Bs[cur][(wn * 64 + i * 16 + fr) * 32 + fg * 8]);
    }
    __builtin_amdgcn_s_setprio(1);
#pragma unroll
    for (int mi = 0; mi < 4; ++mi)
#pragma unroll
      for (int ni = 0; ni < 4; ++ni)
        acc[mi][ni] = mfma16(af[mi], bfr[ni], acc[mi][ni]);
    __builtin_amdgcn_s_setprio(0);

    asm volatile("s_waitcnt vmcnt(0)" ::: "memory");
    __syncthreads();
  }
#undef QKV_STAGE

  const float scale = (z == 0) ? 0.18033688011112042f : 1.0f;  // 0.125*log2(e)
#pragma unroll
  for (int mi = 0; mi < 4; ++mi)
#pragma unroll
    for (int ni = 0; ni < 4; ++ni) {
      const int col = n0 + wn * 64 + ni * 16 + fr;
      const float bval = bias[col];
      const int h = col >> 6, d = col & 63;
#pragma unroll
      for (int r = 0; r < 4; ++r) {
        const int row = m0 + wm * 64 + mi * 16 + fg * 4 + r;
        const float val = (acc[mi][ni][r] + bval) * scale;
        const int b = row >> 11, s = row & (SS - 1);
        if (z < 2) {
          short* dst = (z == 0) ? Qh : Kh;
          dst[((size_t)(b * NH + h) * SS + s) * DK + d] = to_bf16(val);
        } else {
          VT[((size_t)(b * NH + h) * DK + d) * SS + s] = to_bf16(val);
        }
      }
    }
}

// ---------------- O-projection: 128x64 tiles, BK=32 dbuf, f32 out ----------
__global__ __launch_bounds__(256) void gemm_out(const short* __restrict__ A,
                                                const short* __restrict__ Wt,
                                                const float* __restrict__ bias,
                                                float* __restrict__ Y) {
  constexpr int K = 1024, NSTEP = K / 32;
  __shared__ short As[2][128 * 32];
  __shared__ short Bs[2][64 * 32];
  const int tid = threadIdx.x;
  const int w = tid >> 6, lane = tid & 63;
  const int m0 = blockIdx.x * 128, n0 = blockIdx.y * 64;
  const int wm = w >> 1, wn = w & 1;
  const int fr = lane & 15, fg = lane >> 4;
  const int srow = tid >> 2, scol = (tid & 3) * 8;

  f32x4 acc[4][2] = {};

#define OUT_STAGE(buf, k0)                                                    \
  do {                                                                        \
    _Pragma("unroll") for (int i = 0; i < 2; ++i) {                           \
      const int row = i * 64 + srow;                                          \
      gload_lds16(A + (size_t)(m0 + row) * K + (k0) + scol,                   \
                  &As[buf][row * 32 + scol]);                                 \
    }                                                                         \
    if (srow < 64)                                                            \
      gload_lds16(Wt + (size_t)(n0 + srow) * K + (k0) + scol,                 \
                  &Bs[buf][srow * 32 + scol]);                                \
  } while (0)

  OUT_STAGE(0, 0);
  asm volatile("s_waitcnt vmcnt(0)" ::: "memory");
  __syncthreads();

  for (int t = 0; t < NSTEP; ++t) {
    const int cur = t & 1;
    if (t + 1 < NSTEP) OUT_STAGE(cur ^ 1, (t + 1) * 32);

    bf16x8 af[4], bfr[2];
#pragma unroll
    for (int i = 0; i < 4; ++i)
      af[i] = *(const bf16x8*)(&As[cur][(wm * 64 + i * 16 + fr) * 32 + fg * 8]);
#pragma unroll
    for (int i = 0; i < 2; ++i)
      bfr[i] = *(const bf16x8*)(&Bs[cur][(wn * 32 + i * 16 + fr) * 32 + fg * 8]);
    __builtin_amdgcn_s_setprio(1);
#pragma unroll
    for (int mi = 0; mi < 4; ++mi)
#pragma unroll
      for (int ni = 0; ni < 2; ++ni)
        acc[mi][ni] = mfma16(af[mi], bfr[ni], acc[mi][ni]);
    __builtin_amdgcn_s_setprio(0);

    asm volatile("s_waitcnt vmcnt(0)" ::: "memory");
    __syncthreads();
  }
#undef OUT_STAGE

#pragma unroll
  for (int mi = 0; mi < 4; ++mi)
#pragma unroll
    for (int ni = 0; ni < 2; ++ni) {
      const int col = n0 + wn * 32 + ni * 16 + fr;
      const float bval = bias[col];
#pragma unroll
      for (int r = 0; r < 4; ++r) {
        const int row = m0 + wm * 64 + mi * 16 + fg * 4 + r;
        Y[(size_t)row * D_MODEL + col] = acc[mi][ni][r] + bval;
      }
    }
}

// ---------------- causal flash attention, pipelined balanced pairs ---------
// (unchanged from R8) Block = strips {j, 31-j} sequential (33 tiles); 512
// blocks; 4 waves x 16 q rows. body(g) = QK(g) MFMA || softmax(g-1)+PV(g-1),
// then vmcnt(0)+barrier, then stage(g+2) into triple-buffered K/V LDS.
__global__ __launch_bounds__(256) void attn_kernel(const short* __restrict__ Qh,
                                                   const short* __restrict__ Kh,
                                                   const short* __restrict__ VT,
                                                   short* __restrict__ AO) {
  __shared__ short Ks[3][64 * 64];     // [buf][key-row][d], swizzled, 24 KB
  __shared__ short Vs[3][64 * 64];     // [buf][d-row][key], swizzled, 24 KB
  __shared__ short P_lds[4][16 * 64];  // wave-private P^T, 8 KB

  const int tid = threadIdx.x, w = tid >> 6, lane = tid & 63;
  const int fr = lane & 15, fg = lane >> 4;
  const int kr = fg * 4;
  const int swz = (fr & 7) << 4;

  const int bid = blockIdx.x;
  const int lid = ((bid & 7) << 6) | (bid >> 3);
  const int bh = lid >> 4;      // 0..31
  const int j = lid & 15;       // pair index: strips {j, 31-j}
  const int b = bh >> 4, h = bh & 15;

  const short* Qp = Qh + (size_t)bh * SS * DK;
  const short* Kp = Kh + (size_t)bh * SS * DK;
  const short* Vp = VT + (size_t)bh * DK * SS;

  const int sc_c = tid & 7;    // 16B chunk within 128B row
  const int sc_r = tid >> 3;   // row 0..31 (pass adds 32)

  const int T0 = j + 1;        // segment-0 tiles; segment-1 = 32-j; total 33

  bf16x8 qf[2];
#pragma unroll
  for (int hh = 0; hh < 2; ++hh)
    qf[hh] = *(const bf16x8*)(Qp + (size_t)(j * 64 + w * 16 + fr) * DK + hh * 32 + fg * 8);

  const short onev = (fr == 0) ? (short)0x3F80 : (short)0;
  const bf16x8 af4 = {onev, onev, onev, onev, onev, onev, onev, onev};

  f32x4 o[5] = {};  // d-tiles 0..3 + l-sum; lane holds O^T[d=t*16+kr+r][q=fr]
  float m_run = -1e30f;
  f32x4 stA[4], stB[4];

#define KK0(g) ((((g) < T0) ? (g) : ((g) - T0)) * 64)
#define STAGE_KV(buf, kk0)                                                    \
  do {                                                                        \
    _Pragma("unroll") for (int p = 0; p < 2; ++p) {                           \
      const int row = p * 32 + sc_r;                                          \
      const int sc = sc_c ^ (row & 7);                                        \
      gload_lds16(Kp + (size_t)((kk0) + row) * DK + sc * 8,                   \
                  &Ks[buf][row * 64 + sc_c * 8]);                             \
      gload_lds16(Vp + (size_t)row * SS + (kk0) + sc * 8,                     \
                  &Vs[buf][row * 64 + sc_c * 8]);                             \
    }                                                                         \
  } while (0)

  auto softmax_pv = [&](int bufPrev) {
    float p0 = max3f(stB[0][0], stB[0][1], stB[0][2]);
    float p1 = max3f(stB[0][3], stB[1][0], stB[1][1]);
    float p2 = max3f(stB[1][2], stB[1][3], stB[2][0]);
    float p3 = max3f(stB[2][1], stB[2][2], stB[2][3]);
    float p4 = max3f(stB[3][0], stB[3][1], stB[3][2]);
    float pmax = fmaxf(max3f(p0, p1, p2), max3f(p3, p4, stB[3][3]));
    pmax = fmaxf(pmax, __shfl_xor(pmax, 16));
    pmax = fmaxf(pmax, __shfl_xor(pmax, 32));

    if (!__all(pmax <= m_run + 11.0f)) {
      const float mn = fmaxf(m_run, pmax);
      const float al = __builtin_amdgcn_exp2f(m_run - mn);
      m_run = mn;
#pragma unroll
      for (int t = 0; t < 5; ++t)
#pragma unroll
        for (int r = 0; r < 4; ++r) o[t][r] *= al;
    }

    char* base = (char*)P_lds[w];
#pragma unroll
    for (int kt = 0; kt < 4; ++kt) {
      short4 sv;
      sv.x = to_bf16(__builtin_amdgcn_exp2f(stB[kt][0] - m_run));
      sv.y = to_bf16(__builtin_amdgcn_exp2f(stB[kt][1] - m_run));
      sv.z = to_bf16(__builtin_amdgcn_exp2f(stB[kt][2] - m_run));
      sv.w = to_bf16(__builtin_amdgcn_exp2f(stB[kt][3] - m_run));
      *(short4*)(base + ((fr * 128 + kt * 32 + fg * 8) ^ swz)) = sv;
    }
    asm volatile("s_waitcnt lgkmcnt(0)" ::: "memory");

    const char* VsB = (const char*)Vs[bufPrev];
    __builtin_amdgcn_s_setprio(1);
#pragma unroll
    for (int c = 0; c < 2; ++c) {
      const bf16x8 pf = *(const bf16x8*)((const char*)P_lds[w] +
                                         ((fr * 128 + c * 64 + fg * 16) ^ swz));
#pragma unroll
      for (int t = 0; t < 4; ++t) {
        const bf16x8 vfb = *(const bf16x8*)(VsB + (t * 16 + fr) * 128 +
                                            ((c * 64 + fg * 16) ^ swz));
        o[t] = mfma16(vfb, pf, o[t]);
      }
      o[4] = mfma16(af4, pf, o[4]);
    }
    __builtin_amdgcn_s_setprio(0);
  };

  auto store_o = [&](int qbase) {
    const float l = __shfl(o[4][0], fr);
    const float inv = 1.0f / l;
    const int s = qbase + w * 16 + fr;
#pragma unroll
    for (int t = 0; t < 4; ++t) {
      short4 ov = {to_bf16(o[t][0] * inv), to_bf16(o[t][1] * inv),
                   to_bf16(o[t][2] * inv), to_bf16(o[t][3] * inv)};
      *(short4*)(AO + (size_t)(b * SS + s) * D_MODEL + h * 64 + t * 16 + kr) = ov;
    }
  };

  STAGE_KV(0, 0);
  STAGE_KV(1, KK0(1));
  asm volatile("s_waitcnt vmcnt(0)" ::: "memory");
  __syncthreads();

  for (int g = 0; g < 33; ++g) {
    if (g == T0) {
#pragma unroll
      for (int hh = 0; hh < 2; ++hh)
        qf[hh] = *(const bf16x8*)(Qp + (size_t)((31 - j) * 64 + w * 16 + fr) * DK + hh * 32 + fg * 8);
    }

    {
      const char* KsB = (const char*)Ks[g % 3];
      __builtin_amdgcn_s_setprio(1);
#pragma unroll
      for (int kt = 0; kt < 4; ++kt) {
        const bf16x8 k0f = *(const bf16x8*)(KsB + (kt * 16 + fr) * 128 + ((fg * 16) ^ swz));
        const bf16x8 k1f = *(const bf16x8*)(KsB + (kt * 16 + fr) * 128 + ((64 + fg * 16) ^ swz));
        f32x4 z = {};
        z = mfma16(k0f, qf[0], z);
        z = mfma16(k1f, qf[1], z);
        stA[kt] = z;
      }
      __builtin_amdgcn_s_setprio(0);
    }
    if (g == T0 - 1 || g == 32) {
#pragma unroll
      for (int kt = 0; kt < 4; ++kt)
#pragma unroll
        for (int r = 0; r < 4; ++r)
          if (kt * 16 + kr + r > w * 16 + fr) stA[kt][r] = -1e30f;
    }

    if (g > 0) {
      softmax_pv((g - 1) % 3);
      if (g == T0) {
        store_o(j * 64);
#pragma unroll
        for (int t = 0; t < 5; ++t)
#pragma unroll
          for (int r = 0; r < 4; ++r) o[t][r] = 0.f;
        m_run = -1e30f;
      }
    }

#pragma unroll
    for (int kt = 0; kt < 4; ++kt) stB[kt] = stA[kt];

    asm volatile("s_waitcnt vmcnt(0)" ::: "memory");
    __syncthreads();
    if (g + 2 <= 32) STAGE_KV((g + 2) % 3, KK0(g + 2));
  }

  softmax_pv(32 % 3);
  store_o((31 - j) * 64);
#undef STAGE_KV
#undef KK0
}

extern "C" void kernel_launch(void* const* d_in, const int* in_sizes, int n_in,
                              void* d_out, int out_size, void* d_ws, size_t ws_size,
                              hipStream_t stream) {
  const float* q  = (const float*)d_in[0];
  const float* k  = (const float*)d_in[1];
  const float* v  = (const float*)d_in[2];
  const float* Wq = (const float*)d_in[4];
  const float* bq = (const float*)d_in[5];
  const float* Wk = (const float*)d_in[6];
  const float* bk = (const float*)d_in[7];
  const float* Wv = (const float*)d_in[8];
  const float* bv = (const float*)d_in[9];
  const float* Wo = (const float*)d_in[10];
  const float* bo = (const float*)d_in[11];

  char* ws = (char*)d_ws;
  const size_t MB = 1u << 20;
  short* Xq = (short*)(ws + 0 * MB);
  short* Xk = (short*)(ws + 8 * MB);
  short* Xv = (short*)(ws + 16 * MB);
  short* Bq = (short*)(ws + 24 * MB);
  short* Bk = (short*)(ws + 26 * MB);
  short* Bv = (short*)(ws + 28 * MB);
  short* Bo = (short*)(ws + 30 * MB);
  short* Qh = (short*)(ws + 32 * MB);
  short* Kh = (short*)(ws + 40 * MB);
  short* VT = (short*)(ws + 48 * MB);
  short* AO = (short*)(ws + 56 * MB);

  cvt3<<<dim3(MROWS * D_MODEL / 1024, 1, 3), 256, 0, stream>>>(q, k, v, Xq, Xk, Xv);
  cvt4<<<dim3(D_MODEL * D_MODEL / 1024, 1, 4), 256, 0, stream>>>(Wq, Wk, Wv, Wo, Bq, Bk, Bv, Bo);

  gemm_qkv<<<dim3(MROWS / 128, D_MODEL / 128, 3), 256, 0, stream>>>(
      Xq, Xk, Xv, Bq, Bk, Bv, bq, bk, bv, Qh, Kh, VT);

  attn_kernel<<<dim3(512), 256, 0, stream>>>(Qh, Kh, VT, AO);

  gemm_out<<<dim3(MROWS / 128, D_MODEL / 64), 256, 0, stream>>>(AO, Bo, bo, (float*)d_out);
}

// Round 10
// 120.070 us; speedup vs baseline: 1.2358x; 1.0258x over previous
//
#include <hip/hip_runtime.h>
#include <hip/hip_bf16.h>
#include <stdint.h>

#define D_MODEL 1024
#define NH 16
#define DK 64
#define BB 2
#define SS 2048
#define MROWS (BB*SS)  // 4096

typedef __attribute__((ext_vector_type(8))) short bf16x8;
typedef __attribute__((ext_vector_type(4))) float f32x4;

__device__ __forceinline__ short to_bf16(float f) {
  __hip_bfloat16 h = __float2bfloat16(f);
  union { __hip_bfloat16 b; short s; } u; u.b = h; return u.s;
}

__device__ __forceinline__ f32x4 mfma16(bf16x8 a, bf16x8 b, f32x4 c) {
  return __builtin_amdgcn_mfma_f32_16x16x32_bf16(a, b, c, 0, 0, 0);
}

__device__ __forceinline__ void gload_lds16(const void* g, void* l) {
  __builtin_amdgcn_global_load_lds(
      (const __attribute__((address_space(1))) unsigned int*)g,
      (__attribute__((address_space(3))) unsigned int*)l,
      16, 0, 0);
}

__device__ __forceinline__ float max3f(float a, float b, float c) {
  return fmaxf(fmaxf(a, b), c);  // clang fuses to v_max3_f32
}

// ---------------- batched f32 -> bf16 converts ----------------
__global__ __launch_bounds__(256) void cvt3(const float* __restrict__ a,
                                            const float* __restrict__ b,
                                            const float* __restrict__ c,
                                            short* __restrict__ oa,
                                            short* __restrict__ ob,
                                            short* __restrict__ oc) {
  const int z = blockIdx.z;
  const float* x = z == 0 ? a : z == 1 ? b : c;
  short* y = z == 0 ? oa : z == 1 ? ob : oc;
  const int i = (blockIdx.x * 256 + threadIdx.x) * 4;
  const float4 v = *(const float4*)(x + i);
  short4 o;
  o.x = to_bf16(v.x); o.y = to_bf16(v.y); o.z = to_bf16(v.z); o.w = to_bf16(v.w);
  *(short4*)(y + i) = o;
}

__global__ __launch_bounds__(256) void cvt4(const float* __restrict__ a,
                                            const float* __restrict__ b,
                                            const float* __restrict__ c,
                                            const float* __restrict__ d,
                                            short* __restrict__ oa,
                                            short* __restrict__ ob,
                                            short* __restrict__ oc,
                                            short* __restrict__ od) {
  const int z = blockIdx.z;
  const float* x = z == 0 ? a : z == 1 ? b : z == 2 ? c : d;
  short* y = z == 0 ? oa : z == 1 ? ob : z == 2 ? oc : od;
  const int i = (blockIdx.x * 256 + threadIdx.x) * 4;
  const float4 v = *(const float4*)(x + i);
  short4 o;
  o.x = to_bf16(v.x); o.y = to_bf16(v.y); o.z = to_bf16(v.z); o.w = to_bf16(v.w);
  *(short4*)(y + i) = o;
}

// ---------------- batched QKV projection: Y = X * W^T + b ------------------
// BK=32, TRIPLE-buffered LDS, 2-deep stage-ahead with counted vmcnt(4):
// stage(t+2) issued at loop top, wait leaves its 4 loads in flight.
// z=0: Q -> (b,h,s,dk) scaled by 0.125*log2(e);  z=1: K -> (b,h,s,dk);
// z=2: V -> (b,h,dk,s) via coalescing LDS transpose epilogue.
__global__ __launch_bounds__(256) void gemm_qkv(const short* __restrict__ Xq,
                                                const short* __restrict__ Xk,
                                                const short* __restrict__ Xv,
                                                const short* __restrict__ Wq,
                                                const short* __restrict__ Wk,
                                                const short* __restrict__ Wv,
                                                const float* __restrict__ bq,
                                                const float* __restrict__ bk,
                                                const float* __restrict__ bv,
                                                short* __restrict__ Qh,
                                                short* __restrict__ Kh,
                                                short* __restrict__ VT) {
  constexpr int K = 1024, NSTEP = K / 32;
  __shared__ __align__(16) char pool[49152];  // 3 x (As 8KB + Bs 8KB); reused for transpose
  const int z = blockIdx.z;
  const short* A    = z == 0 ? Xq : z == 1 ? Xk : Xv;
  const short* Wt   = z == 0 ? Wq : z == 1 ? Wk : Wv;
  const float* bias = z == 0 ? bq : z == 1 ? bk : bv;

  const int tid = threadIdx.x;
  const int w = tid >> 6, lane = tid & 63;
  const int m0 = blockIdx.x * 128, n0 = blockIdx.y * 128;
  const int wm = w >> 1, wn = w & 1;
  const int fr = lane & 15, fg = lane >> 4;
  const int srow = tid >> 2, scol = (tid & 3) * 8;

  f32x4 acc[4][4] = {};

#define QKV_STAGE(buf, k0)                                                    \
  do {                                                                        \
    short* As_ = (short*)(pool + (buf) * 16384);                              \
    short* Bs_ = (short*)(pool + (buf) * 16384 + 8192);                       \
    _Pragma("unroll") for (int i = 0; i < 2; ++i) {                           \
      const int row = i * 64 + srow;                                          \
      gload_lds16(A  + (size_t)(m0 + row) * K + (k0) + scol,                  \
                  As_ + row * 32 + scol);                                     \
      gload_lds16(Wt + (size_t)(n0 + row) * K + (k0) + scol,                  \
                  Bs_ + row * 32 + scol);                                     \
    }                                                                         \
  } while (0)

  QKV_STAGE(0, 0);
  QKV_STAGE(1, 32);
  asm volatile("s_waitcnt vmcnt(4)" ::: "memory");  // buf0 ready, buf1 in flight
  __syncthreads();

  for (int t = 0; t < NSTEP; ++t) {
    if (t + 2 < NSTEP) QKV_STAGE((t + 2) % 3, (t + 2) * 32);

    const short* Ab = (const short*)(pool + (t % 3) * 16384);
    const short* Bb = (const short*)(pool + (t % 3) * 16384 + 8192);
    bf16x8 af[4], bfr[4];
#pragma unroll
    for (int i = 0; i < 4; ++i) {
      af[i]  = *(const bf16x8*)(Ab + (wm * 64 + i * 16 + fr) * 32 + fg * 8);
      bfr[i] = *(const bf16x8*)(Bb + (wn * 64 + i * 16 + fr) * 32 + fg * 8);
    }
    __builtin_amdgcn_s_setprio(1);
#pragma unroll
    for (int mi = 0; mi < 4; ++mi)
#pragma unroll
      for (int ni = 0; ni < 4; ++ni)
        acc[mi][ni] = mfma16(af[mi], bfr[ni], acc[mi][ni]);
    __builtin_amdgcn_s_setprio(0);

    if (t + 2 < NSTEP)
      asm volatile("s_waitcnt vmcnt(4)" ::: "memory");  // drain t+1, keep t+2
    else
      asm volatile("s_waitcnt vmcnt(0)" ::: "memory");
    __syncthreads();
  }
#undef QKV_STAGE

  if (z < 2) {
    const float scale = (z == 0) ? 0.18033688011112042f : 1.0f;  // 0.125*log2(e)
    short* dst = (z == 0) ? Qh : Kh;
#pragma unroll
    for (int mi = 0; mi < 4; ++mi)
#pragma unroll
      for (int ni = 0; ni < 4; ++ni) {
        const int col = n0 + wn * 64 + ni * 16 + fr;
        const float bval = bias[col];
        const int h = col >> 6, d = col & 63;
#pragma unroll
        for (int r = 0; r < 4; ++r) {
          const int row = m0 + wm * 64 + mi * 16 + fg * 4 + r;
          const float val = (acc[mi][ni][r] + bval) * scale;
          const int b = row >> 11, s = row & (SS - 1);
          dst[((size_t)(b * NH + h) * SS + s) * DK + d] = to_bf16(val);
        }
      }
  } else {
    // V^T: transpose 128x128 tile through LDS, then 16B-coalesced stores.
    short* trs = (short*)pool;  // [d_local][s_local swizzled], 32 KB
#pragma unroll
    for (int mi = 0; mi < 4; ++mi)
#pragma unroll
      for (int ni = 0; ni < 4; ++ni) {
        const int dl = wn * 64 + ni * 16 + fr;
        const int s0 = wm * 64 + mi * 16 + fg * 4;
        const float bval = bias[n0 + dl];
        short4 sv = {to_bf16(acc[mi][ni][0] + bval), to_bf16(acc[mi][ni][1] + bval),
                     to_bf16(acc[mi][ni][2] + bval), to_bf16(acc[mi][ni][3] + bval)};
        *(short4*)(trs + dl * 128 + (s0 ^ ((dl & 7) << 3))) = sv;
      }
    __syncthreads();
    const int b = m0 >> 11, sbase = m0 & (SS - 1);
#pragma unroll
    for (int rep = 0; rep < 8; ++rep) {
      const int dl = (tid >> 4) + rep * 16;
      const int s0 = (tid & 15) * 8;
      const bf16x8 vv = *(const bf16x8*)(trs + dl * 128 + (s0 ^ ((dl & 7) << 3)));
      const int col = n0 + dl;
      const int h = col >> 6, d = col & 63;
      *(bf16x8*)(VT + ((size_t)(b * NH + h) * DK + d) * SS + sbase + s0) = vv;
    }
  }
}

// ---------------- O-projection: 128x64, BK=32, tbuf + counted vmcnt --------
__global__ __launch_bounds__(256) void gemm_out(const short* __restrict__ A,
                                                const short* __restrict__ Wt,
                                                const float* __restrict__ bias,
                                                float* __restrict__ Y) {
  constexpr int K = 1024, NSTEP = K / 32;
  __shared__ __align__(16) char pool[36864];  // 3 x (As 8KB + Bs 4KB)
  const int tid = threadIdx.x;
  const int w = tid >> 6, lane = tid & 63;
  const int m0 = blockIdx.x * 128, n0 = blockIdx.y * 64;
  const int wm = w >> 1, wn = w & 1;
  const int fr = lane & 15, fg = lane >> 4;
  const int srow = tid >> 2, scol = (tid & 3) * 8;

  f32x4 acc[4][2] = {};

#define OUT_STAGE(buf, k0)                                                    \
  do {                                                                        \
    short* As_ = (short*)(pool + (buf) * 12288);                              \
    short* Bs_ = (short*)(pool + (buf) * 12288 + 8192);                       \
    _Pragma("unroll") for (int i = 0; i < 2; ++i) {                           \
      const int row = i * 64 + srow;                                          \
      gload_lds16(A + (size_t)(m0 + row) * K + (k0) + scol,                   \
                  As_ + row * 32 + scol);                                     \
    }                                                                         \
    gload_lds16(Wt + (size_t)(n0 + srow) * K + (k0) + scol,                   \
                Bs_ + srow * 32 + scol);                                      \
  } while (0)

  OUT_STAGE(0, 0);
  OUT_STAGE(1, 32);
  asm volatile("s_waitcnt vmcnt(3)" ::: "memory");
  __syncthreads();

  for (int t = 0; t < NSTEP; ++t) {
    if (t + 2 < NSTEP) OUT_STAGE((t + 2) % 3, (t + 2) * 32);

    const short* Ab = (const short*)(pool + (t % 3) * 12288);
    const short* Bb = (const short*)(pool + (t % 3) * 12288 + 8192);
    bf16x8 af[4], bfr[2];
#pragma unroll
    for (int i = 0; i < 4; ++i)
      af[i] = *(const bf16x8*)(Ab + (wm * 64 + i * 16 + fr) * 32 + fg * 8);
#pragma unroll
    for (int i = 0; i < 2; ++i)
      bfr[i] = *(const bf16x8*)(Bb + (wn * 32 + i * 16 + fr) * 32 + fg * 8);
    __builtin_amdgcn_s_setprio(1);
#pragma unroll
    for (int mi = 0; mi < 4; ++mi)
#pragma unroll
      for (int ni = 0; ni < 2; ++ni)
        acc[mi][ni] = mfma16(af[mi], bfr[ni], acc[mi][ni]);
    __builtin_amdgcn_s_setprio(0);

    if (t + 2 < NSTEP)
      asm volatile("s_waitcnt vmcnt(3)" ::: "memory");
    else
      asm volatile("s_waitcnt vmcnt(0)" ::: "memory");
    __syncthreads();
  }
#undef OUT_STAGE

#pragma unroll
  for (int mi = 0; mi < 4; ++mi)
#pragma unroll
    for (int ni = 0; ni < 2; ++ni) {
      const int col = n0 + wn * 32 + ni * 16 + fr;
      const float bval = bias[col];
#pragma unroll
      for (int r = 0; r < 4; ++r) {
        const int row = m0 + wm * 64 + mi * 16 + fg * 4 + r;
        Y[(size_t)row * D_MODEL + col] = acc[mi][ni][r] + bval;
      }
    }
}

// ---------------- causal flash attention, KVBLK=128, counted vmcnt ---------
// Block = strip pair {j, 31-j} sequential -> exactly 17 tiles of 128 keys.
// 512 blocks; 4 waves x 16 q. Per body(g): issue K(g+1) at top (window =
// full body), QK(g) both halves, softmax_pv(g-1), barrier, issue V(g+1),
// vmcnt(4) leaves V(g+1) in flight. K/V double-buffered; one barrier/tile.
__global__ __launch_bounds__(256) void attn_kernel(const short* __restrict__ Qh,
                                                   const short* __restrict__ Kh,
                                                   const short* __restrict__ VT,
                                                   short* __restrict__ AO) {
  __shared__ short Ks[2][2][64 * 64];  // [buf][half][key(0..63)][d], swizzled, 32 KB
  __shared__ short Vs[2][2][64 * 64];  // [buf][half][d][key], swizzled, 32 KB
  __shared__ short P_lds[4][16 * 64];  // wave-private P^T, 8 KB

  const int tid = threadIdx.x, w = tid >> 6, lane = tid & 63;
  const int fr = lane & 15, fg = lane >> 4;
  const int kr = fg * 4;
  const int swz = (fr & 7) << 4;

  const int bid = blockIdx.x;
  const int lid = ((bid & 7) << 6) | (bid >> 3);
  const int bh = lid >> 4;      // 0..31
  const int j = lid & 15;       // pair {j, 31-j}
  const int b = bh >> 4, h = bh & 15;

  const short* Qp = Qh + (size_t)bh * SS * DK;
  const short* Kp = Kh + (size_t)bh * SS * DK;
  const short* Vp = VT + (size_t)bh * DK * SS;

  const int sc_c = tid & 7;    // 16B chunk within 128B row
  const int sc_r = tid >> 3;   // row 0..31 (pass adds 32)

  const int T0 = (j + 2) >> 1;          // seg0 tiles; T1 = 17 - T0
  const int koff0 = j * 64 - (T0 - 1) * 128;          // 0 or 64
  const int koff1 = (31 - j) * 64 - (16 - T0) * 128;  // 64 or 0

  bf16x8 qf[2];
#pragma unroll
  for (int hh = 0; hh < 2; ++hh)
    qf[hh] = *(const bf16x8*)(Qp + (size_t)(j * 64 + w * 16 + fr) * DK + hh * 32 + fg * 8);

  const short onev = (fr == 0) ? (short)0x3F80 : (short)0;
  const bf16x8 af4 = {onev, onev, onev, onev, onev, onev, onev, onev};

  f32x4 o[5] = {};
  float m_run = -1e30f;
  f32x4 stA[8], stB[8];  // [half*4 + kt]

#define KK0(g) ((((g) < T0) ? (g) : ((g) - T0)) * 128)
#define STAGE_K(buf, kk0)                                                     \
  do {                                                                        \
    _Pragma("unroll") for (int hf = 0; hf < 2; ++hf)                          \
    _Pragma("unroll") for (int p = 0; p < 2; ++p) {                           \
      const int row = p * 32 + sc_r;                                          \
      const int sc = sc_c ^ (row & 7);                                        \
      gload_lds16(Kp + (size_t)((kk0) + hf * 64 + row) * DK + sc * 8,         \
                  &Ks[buf][hf][row * 64 + sc_c * 8]);                         \
    }                                                                         \
  } while (0)
#define STAGE_V(buf, kk0)                                                     \
  do {                                                                        \
    _Pragma("unroll") for (int hf = 0; hf < 2; ++hf)                          \
    _Pragma("unroll") for (int p = 0; p < 2; ++p) {                           \
      const int row = p * 32 + sc_r;                                          \
      const int sc = sc_c ^ (row & 7);                                        \
      gload_lds16(Vp + (size_t)row * SS + (kk0) + hf * 64 + sc * 8,           \
                  &Vs[buf][hf][row * 64 + sc_c * 8]);                         \
    }                                                                         \
  } while (0)

  auto softmax_pv = [&](int bufPrev) {
    float mm[8];
#pragma unroll
    for (int i = 0; i < 8; ++i)
      mm[i] = fmaxf(fmaxf(stB[i][0], stB[i][1]), fmaxf(stB[i][2], stB[i][3]));
    float pmax = fmaxf(max3f(mm[0], mm[1], mm[2]),
                       fmaxf(max3f(mm[3], mm[4], mm[5]), fmaxf(mm[6], mm[7])));
    pmax = fmaxf(pmax, __shfl_xor(pmax, 16));
    pmax = fmaxf(pmax, __shfl_xor(pmax, 32));

    if (!__all(pmax <= m_run + 11.0f)) {
      const float mn = fmaxf(m_run, pmax);
      const float al = __builtin_amdgcn_exp2f(m_run - mn);
      m_run = mn;
#pragma unroll
      for (int t = 0; t < 5; ++t)
#pragma unroll
        for (int r = 0; r < 4; ++r) o[t][r] *= al;
    }

#pragma unroll
    for (int hf = 0; hf < 2; ++hf) {
      char* base = (char*)P_lds[w];
#pragma unroll
      for (int kt = 0; kt < 4; ++kt) {
        short4 sv;
        sv.x = to_bf16(__builtin_amdgcn_exp2f(stB[hf * 4 + kt][0] - m_run));
        sv.y = to_bf16(__builtin_amdgcn_exp2f(stB[hf * 4 + kt][1] - m_run));
        sv.z = to_bf16(__builtin_amdgcn_exp2f(stB[hf * 4 + kt][2] - m_run));
        sv.w = to_bf16(__builtin_amdgcn_exp2f(stB[hf * 4 + kt][3] - m_run));
        *(short4*)(base + ((fr * 128 + kt * 32 + fg * 8) ^ swz)) = sv;
      }
      asm volatile("s_waitcnt lgkmcnt(0)" ::: "memory");

      const char* VsB = (const char*)Vs[bufPrev][hf];
      __builtin_amdgcn_s_setprio(1);
#pragma unroll
      for (int c = 0; c < 2; ++c) {
        const bf16x8 pf = *(const bf16x8*)((const char*)P_lds[w] +
                                           ((fr * 128 + c * 64 + fg * 16) ^ swz));
#pragma unroll
        for (int t = 0; t < 4; ++t) {
          const bf16x8 vfb = *(const bf16x8*)(VsB + (t * 16 + fr) * 128 +
                                              ((c * 64 + fg * 16) ^ swz));
          o[t] = mfma16(vfb, pf, o[t]);
        }
        o[4] = mfma16(af4, pf, o[4]);
      }
      __builtin_amdgcn_s_setprio(0);
    }
  };

  auto store_o = [&](int qbase) {
    const float l = __shfl(o[4][0], fr);
    const float inv = 1.0f / l;
    const int s = qbase + w * 16 + fr;
#pragma unroll
    for (int t = 0; t < 4; ++t) {
      short4 ov = {to_bf16(o[t][0] * inv), to_bf16(o[t][1] * inv),
                   to_bf16(o[t][2] * inv), to_bf16(o[t][3] * inv)};
      *(short4*)(AO + (size_t)(b * SS + s) * D_MODEL + h * 64 + t * 16 + kr) = ov;
    }
  };

  STAGE_K(0, 0);
  STAGE_V(0, 0);
  asm volatile("s_waitcnt vmcnt(0)" ::: "memory");
  __syncthreads();

  for (int g = 0; g < 17; ++g) {
    if (g == T0) {  // segment-1 Q
#pragma unroll
      for (int hh = 0; hh < 2; ++hh)
        qf[hh] = *(const bf16x8*)(Qp + (size_t)((31 - j) * 64 + w * 16 + fr) * DK + hh * 32 + fg * 8);
    }

    if (g + 1 < 17) STAGE_K((g + 1) & 1, KK0(g + 1));  // full-body window

    // QK(g): both halves
    {
      __builtin_amdgcn_s_setprio(1);
#pragma unroll
      for (int hf = 0; hf < 2; ++hf) {
        const char* KsB = (const char*)Ks[g & 1][hf];
#pragma unroll
        for (int kt = 0; kt < 4; ++kt) {
          const bf16x8 k0f = *(const bf16x8*)(KsB + (kt * 16 + fr) * 128 + ((fg * 16) ^ swz));
          const bf16x8 k1f = *(const bf16x8*)(KsB + (kt * 16 + fr) * 128 + ((64 + fg * 16) ^ swz));
          f32x4 zz = {};
          zz = mfma16(k0f, qf[0], zz);
          zz = mfma16(k1f, qf[1], zz);
          stA[hf * 4 + kt] = zz;
        }
      }
      __builtin_amdgcn_s_setprio(0);
    }
    if (g == T0 - 1 || g == 16) {  // diagonal tile of seg0 / seg1
      const int koff = (g == 16) ? koff1 : koff0;
#pragma unroll
      for (int hf = 0; hf < 2; ++hf)
#pragma unroll
        for (int kt = 0; kt < 4; ++kt)
#pragma unroll
          for (int r = 0; r < 4; ++r)
            if (hf * 64 + kt * 16 + kr + r > koff + w * 16 + fr)
              stA[hf * 4 + kt][r] = -1e30f;
    }

    if (g > 0) {
      softmax_pv((g - 1) & 1);
      if (g == T0) {
        store_o(j * 64);
#pragma unroll
        for (int t = 0; t < 5; ++t)
#pragma unroll
          for (int r = 0; r < 4; ++r) o[t][r] = 0.f;
        m_run = -1e30f;
      }
    }

#pragma unroll
    for (int i = 0; i < 8; ++i) stB[i] = stA[i];

    __syncthreads();
    if (g + 1 < 17) {
      STAGE_V((g + 1) & 1, KK0(g + 1));
      asm volatile("s_waitcnt vmcnt(4)" ::: "memory");  // drain V(g)+K(g+1), keep V(g+1)
    } else {
      asm volatile("s_waitcnt vmcnt(0)" ::: "memory");  // drain V(16) for epilogue
    }
  }

  softmax_pv(16 & 1);
  store_o((31 - j) * 64);
#undef STAGE_K
#undef STAGE_V
#undef KK0
}

extern "C" void kernel_launch(void* const* d_in, const int* in_sizes, int n_in,
                              void* d_out, int out_size, void* d_ws, size_t ws_size,
                              hipStream_t stream) {
  const float* q  = (const float*)d_in[0];
  const float* k  = (const float*)d_in[1];
  const float* v  = (const float*)d_in[2];
  const float* Wq = (const float*)d_in[4];
  const float* bq = (const float*)d_in[5];
  const float* Wk = (const float*)d_in[6];
  const float* bk = (const float*)d_in[7];
  const float* Wv = (const float*)d_in[8];
  const float* bv = (const float*)d_in[9];
  const float* Wo = (const float*)d_in[10];
  const float* bo = (const float*)d_in[11];

  char* ws = (char*)d_ws;
  const size_t MB = 1u << 20;
  short* Xq = (short*)(ws + 0 * MB);
  short* Xk = (short*)(ws + 8 * MB);
  short* Xv = (short*)(ws + 16 * MB);
  short* Bq = (short*)(ws + 24 * MB);
  short* Bk = (short*)(ws + 26 * MB);
  short* Bv = (short*)(ws + 28 * MB);
  short* Bo = (short*)(ws + 30 * MB);
  short* Qh = (short*)(ws + 32 * MB);
  short* Kh = (short*)(ws + 40 * MB);
  short* VT = (short*)(ws + 48 * MB);
  short* AO = (short*)(ws + 56 * MB);

  cvt3<<<dim3(MROWS * D_MODEL / 1024, 1, 3), 256, 0, stream>>>(q, k, v, Xq, Xk, Xv);
  cvt4<<<dim3(D_MODEL * D_MODEL / 1024, 1, 4), 256, 0, stream>>>(Wq, Wk, Wv, Wo, Bq, Bk, Bv, Bo);

  gemm_qkv<<<dim3(MROWS / 128, D_MODEL / 128, 3), 256, 0, stream>>>(
      Xq, Xk, Xv, Bq, Bk, Bv, bq, bk, bv, Qh, Kh, VT);

  attn_kernel<<<dim3(512), 256, 0, stream>>>(Qh, Kh, VT, AO);

  gemm_out<<<dim3(MROWS / 128, D_MODEL / 64), 256, 0, stream>>>(AO, Bo, bo, (float*)d_out);
}